// Round 1
// baseline (2833.828 us; speedup 1.0000x reference)
//
#include <hip/hip_runtime.h>

typedef unsigned short u16;
typedef unsigned int u32;

#define NN 10000      // nodes
#define NE 320000     // edges
#define ET 330000     // edges + self loops
#define NB 262144     // batch

typedef __attribute__((ext_vector_type(8))) short bf16x8;
typedef __attribute__((ext_vector_type(4))) float f32x4;

__device__ __forceinline__ u16 f2b(float f) {
  u32 u = __float_as_uint(f);
  u += 0x7fffu + ((u >> 16) & 1u);
  return (u16)(u >> 16);
}
__device__ __forceinline__ float b2f(u16 h) {
  return __uint_as_float(((u32)h) << 16);
}
__device__ __forceinline__ u32 fkey(float f) {
  u32 u = __float_as_uint(f);
  return (u & 0x80000000u) ? ~u : (u | 0x80000000u);
}
__device__ __forceinline__ float fdecode(u32 k) {
  return __uint_as_float((k & 0x80000000u) ? (k & 0x7fffffffu) : ~k);
}
__device__ __forceinline__ float lrelu(float v, float s) { return v > 0.f ? v : v * s; }

__device__ __forceinline__ void g2lds16(const void* g, void* l) {
  __builtin_amdgcn_global_load_lds((const __attribute__((address_space(1))) void*)g,
                                   (__attribute__((address_space(3))) void*)l, 16, 0, 0);
}

// ---------------- weight conversion ----------------
__global__ __launch_bounds__(256) void k_convw(const float* __restrict__ src, u16* __restrict__ dst,
                                               int M, int Ks, int Kd) {
  int t = blockIdx.x * 256 + threadIdx.x;
  if (t >= M * Kd) return;
  int m = t / Kd, k = t - m * Kd;
  float v = (k < Ks) ? src[(size_t)m * Ks + k] : 0.f;
  dst[t] = f2b(v);
}

__global__ void k_w512(const float* __restrict__ W1, float* __restrict__ w512) {
  w512[threadIdx.x] = W1[(size_t)threadIdx.x * 513 + 512];
}

// ---------------- GAT ----------------
__global__ __launch_bounds__(256) void k_deg(const int* __restrict__ ei, const float* __restrict__ ea,
                                             float* __restrict__ deg, float* __restrict__ asum) {
  int t = blockIdx.x * 256 + threadIdx.x;
  if (t >= NE) return;
  int d = ei[NE + t];
  atomicAdd(&deg[d], 1.f);
  const float* e = ea + (size_t)t * 8;
  float* as = asum + (size_t)d * 8;
#pragma unroll
  for (int j = 0; j < 8; ++j) atomicAdd(&as[j], e[j]);
}

__global__ __launch_bounds__(256) void k_mean(float* __restrict__ asum, const float* __restrict__ deg) {
  int t = blockIdx.x * 256 + threadIdx.x;
  if (t >= NN * 8) return;
  asum[t] /= fmaxf(deg[t >> 3], 1.f);
}

__global__ __launch_bounds__(256) void k_xlr(const float* __restrict__ x,
                                             const float* __restrict__ Wl, const float* __restrict__ bl,
                                             const float* __restrict__ Wr, const float* __restrict__ br,
                                             float* __restrict__ xl, float* __restrict__ xr) {
  __shared__ float sx[128];
  int nb = blockIdx.x * 2;
  for (int i = threadIdx.x; i < 128; i += 256) sx[i] = x[(size_t)nb * 64 + i];
  __syncthreads();
  int half = threadIdx.x >> 7;
  int node = nb + half;
  int m = threadIdx.x & 127;
  const float* xv = sx + (half << 6);
  float al = bl[m], ar = br[m];
  const float* wl = Wl + (size_t)m * 64;
  const float* wr = Wr + (size_t)m * 64;
#pragma unroll 8
  for (int k = 0; k < 64; ++k) { float xk = xv[k]; al += xk * wl[k]; ar += xk * wr[k]; }
  xl[(size_t)node * 128 + m] = al;
  xr[(size_t)node * 128 + m] = ar;
}

__global__ __launch_bounds__(256) void k_scr(const float* __restrict__ xl, const float* __restrict__ xr,
                                             const int* __restrict__ ei, const float* __restrict__ ea,
                                             const float* __restrict__ mattr,
                                             const float* __restrict__ We, const float* __restrict__ att,
                                             float* __restrict__ scr, u32* __restrict__ mxkey) {
  __shared__ float sWeT[8 * 128];
  __shared__ float sAtt[128];
  for (int i = threadIdx.x; i < 1024; i += 256) sWeT[(i & 7) * 128 + (i >> 3)] = We[i];
  if (threadIdx.x < 128) sAtt[threadIdx.x] = att[threadIdx.x];
  __syncthreads();
  int t = blockIdx.x * 256 + threadIdx.x;
  int e = t >> 7, hc = t & 127;
  int s, d; const float* ap;
  if (e < NE) { s = ei[e]; d = ei[NE + e]; ap = ea + (size_t)e * 8; }
  else { s = e - NE; d = s; ap = mattr + (size_t)(e - NE) * 8; }
  float em = 0.f;
#pragma unroll
  for (int j = 0; j < 8; ++j) em += ap[j] * sWeT[j * 128 + hc];
  float v = xl[(size_t)s * 128 + hc] + xr[(size_t)d * 128 + hc] + em;
  v = v > 0.f ? v : 0.2f * v;
  float p = v * sAtt[hc];
#pragma unroll
  for (int off = 16; off; off >>= 1) p += __shfl_xor(p, off);
  if ((hc & 31) == 0) {
    int h = hc >> 5;
    scr[(size_t)e * 4 + h] = p;
    atomicMax(&mxkey[d * 4 + h], fkey(p));
  }
}

__global__ __launch_bounds__(256) void k_exden(float* __restrict__ scr, const int* __restrict__ ei,
                                               const u32* __restrict__ mxkey, float* __restrict__ den) {
  int t = blockIdx.x * 256 + threadIdx.x;
  if (t >= ET * 4) return;
  int e = t >> 2, h = t & 3;
  int d = (e < NE) ? ei[NE + e] : (e - NE);
  float mx = fdecode(mxkey[d * 4 + h]);
  float ex = expf(scr[t] - mx);
  scr[t] = ex;
  atomicAdd(&den[d * 4 + h], ex);
}

__global__ __launch_bounds__(256) void k_scatter(const float* __restrict__ scr, const float* __restrict__ den,
                                                 const int* __restrict__ ei, const float* __restrict__ xl,
                                                 float* __restrict__ nacc, float* __restrict__ aout) {
  int t = blockIdx.x * 256 + threadIdx.x;
  int e = t >> 7, hc = t & 127, h = hc >> 5;
  int s, d;
  if (e < NE) { s = ei[e]; d = ei[NE + e]; }
  else { s = e - NE; d = s; }
  float a = scr[(size_t)e * 4 + h] / den[d * 4 + h];
  if ((hc & 31) == 0) aout[(size_t)e * 4 + h] = a;
  atomicAdd(&nacc[(size_t)d * 128 + hc], a * xl[(size_t)s * 128 + hc]);
}

__global__ __launch_bounds__(256) void k_nodeout(const float* __restrict__ nacc,
                                                 const float* __restrict__ bias,
                                                 float* __restrict__ nout) {
  int t = blockIdx.x * 256 + threadIdx.x;  // NN*128 exact
  int hc = t & 127;
  nout[t] = fmaxf(nacc[t] + bias[hc], 0.f);
}

// ---------------- evo L1 factorization ----------------
__global__ __launch_bounds__(256) void k_qtab(const float* __restrict__ n1, const float* __restrict__ n2,
                                              const float* __restrict__ W1,
                                              float* __restrict__ Qo, float* __restrict__ Qd) {
  __shared__ float s1[1024], s2[1024];
  int nb = blockIdx.x * 8;
  for (int i = threadIdx.x; i < 1024; i += 256) {
    s1[i] = n1[(size_t)nb * 128 + i];
    s2[i] = n2[(size_t)nb * 128 + i];
  }
  __syncthreads();
  int m = threadIdx.x;
  const float* wp = W1 + (size_t)m * 513;
  float qo[8], qd[8];
#pragma unroll
  for (int i = 0; i < 8; ++i) { qo[i] = 0.f; qd[i] = 0.f; }
  for (int k = 0; k < 128; ++k) {
    float w0 = wp[k], w1 = wp[128 + k], w2 = wp[256 + k], w3 = wp[384 + k];
#pragma unroll
    for (int i = 0; i < 8; ++i) {
      qo[i] += s1[i * 128 + k] * w0 + s2[i * 128 + k] * w2;
      qd[i] += s1[i * 128 + k] * w1 + s2[i * 128 + k] * w3;
    }
  }
#pragma unroll
  for (int i = 0; i < 8; ++i) {
    Qo[(size_t)(nb + i) * 256 + m] = qo[i];
    Qd[(size_t)(nb + i) * 256 + m] = qd[i];
  }
}

__global__ __launch_bounds__(256) void k_distb(const int* __restrict__ od, const float* __restrict__ dm,
                                               float* __restrict__ distb) {
  int t = blockIdx.x * 256 + threadIdx.x;
  int o = od[t * 2], d = od[t * 2 + 1];
  distb[t] = dm[(size_t)o * NN + d];
}

__global__ __launch_bounds__(256) void k_evo1(const float* __restrict__ Qo, const float* __restrict__ Qd,
                                              const int* __restrict__ od, const float* __restrict__ distb,
                                              const float* __restrict__ w512, u16* __restrict__ h1) {
  __shared__ float sw[256];
  sw[threadIdx.x] = w512[threadIdx.x];
  __syncthreads();
  int t = blockIdx.x * 256 + threadIdx.x;
  int b = t >> 6, mq = (t & 63) << 2;
  int o = od[b * 2], d = od[b * 2 + 1];
  float dist = distb[b];
  const float4 qa = *(const float4*)(Qo + (size_t)o * 256 + mq);
  const float4 qc = *(const float4*)(Qd + (size_t)d * 256 + mq);
  float v0 = qa.x + qc.x + dist * sw[mq + 0];
  float v1 = qa.y + qc.y + dist * sw[mq + 1];
  float v2 = qa.z + qc.z + dist * sw[mq + 2];
  float v3 = qa.w + qc.w + dist * sw[mq + 3];
  ushort4 r;
  r.x = f2b(lrelu(v0, 0.01f)); r.y = f2b(lrelu(v1, 0.01f));
  r.z = f2b(lrelu(v2, 0.01f)); r.w = f2b(lrelu(v3, 0.01f));
  *(ushort4*)(h1 + (size_t)b * 256 + mq) = r;
}

__global__ __launch_bounds__(256) void k_catx(const int* __restrict__ od, const float* __restrict__ nv,
                                              const float* __restrict__ distb, u16* __restrict__ cat) {
  int b = blockIdx.x * 256 + threadIdx.x;
  int o = od[b * 2], d = od[b * 2 + 1];
  u16* c = cat + (size_t)b * 96 + 64;
  c[0] = f2b(nv[o * 2]);
  c[1] = f2b(nv[d * 2]);
  c[2] = f2b(nv[o * 2 + 1]);
  c[3] = f2b(nv[d * 2 + 1]);
  c[4] = f2b(distb[b]);
#pragma unroll
  for (int k = 5; k < 32; ++k) c[k] = 0;
}

// ---------------- MFMA GEMM: C = A(B x K) @ W(M x K)^T ----------------
// EPI: 0 = leaky->bf16, 1 = raw bf16 + column stats (sum,sumsq), 2 = f32 + bf16 raw
template <int NF, int EPI>
__global__ __launch_bounds__(256) void gemm_bf16(const u16* __restrict__ A, const u16* __restrict__ W,
                                                 int K, int M,
                                                 u16* __restrict__ obf, int ld_bf,
                                                 float* __restrict__ of32, int ld_f32,
                                                 float* __restrict__ stats, float slope) {
  constexpr int CW = NF * 16;   // cols per wave
  constexpr int BN = CW * 2;    // block cols
  __shared__ u16 Alds[128 * 32];
  __shared__ u16 Blds[BN * 32];
  const int lane = threadIdx.x & 63;
  const int w = threadIdx.x >> 6;
  const int wr = w >> 1, wc = w & 1;
  const size_t rowBase = (size_t)blockIdx.x * 128;
  const int colBase = blockIdx.y * BN;

  f32x4 acc[4][NF];
  const f32x4 z4 = {0.f, 0.f, 0.f, 0.f};
#pragma unroll
  for (int m = 0; m < 4; ++m)
#pragma unroll
    for (int n = 0; n < NF; ++n) acc[m][n] = z4;

  const int sr = (w << 4) + (lane >> 2);   // staging row within 64-row group
  const int sc = (lane & 3) << 3;          // staging col (elems)
  const int KT = K >> 5;
  for (int kt = 0; kt < KT; ++kt) {
    const int kb = kt << 5;
#pragma unroll
    for (int i = 0; i < 2; ++i) {
      const u16* src = A + (rowBase + (i << 6) + sr) * (size_t)K + kb + sc;
      g2lds16(src, &Alds[((i << 6) + (w << 4)) << 5]);
    }
#pragma unroll
    for (int i = 0; i < NF / 2; ++i) {
      const u16* src = W + (size_t)(colBase + (i << 6) + sr) * K + kb + sc;
      g2lds16(src, &Blds[((i << 6) + (w << 4)) << 5]);
    }
    __syncthreads();
    const int lr = lane & 15, lk = (lane >> 4) << 3;
    bf16x8 af[4], bfr[NF];
#pragma unroll
    for (int m = 0; m < 4; ++m)
      af[m] = *(const bf16x8*)&Alds[(((wr << 6) + (m << 4) + lr) << 5) + lk];
#pragma unroll
    for (int n = 0; n < NF; ++n)
      bfr[n] = *(const bf16x8*)&Blds[((wc * CW + (n << 4) + lr) << 5) + lk];
#pragma unroll
    for (int m = 0; m < 4; ++m)
#pragma unroll
      for (int n = 0; n < NF; ++n)
        acc[m][n] = __builtin_amdgcn_mfma_f32_16x16x32_bf16(af[m], bfr[n], acc[m][n], 0, 0, 0);
    __syncthreads();
  }

  const int lr = lane & 15, lg = lane >> 4;
  float cs[NF], cq[NF];
#pragma unroll
  for (int n = 0; n < NF; ++n) { cs[n] = 0.f; cq[n] = 0.f; }
#pragma unroll
  for (int m = 0; m < 4; ++m) {
#pragma unroll
    for (int n = 0; n < NF; ++n) {
      const int col = colBase + wc * CW + (n << 4) + lr;
#pragma unroll
      for (int j = 0; j < 4; ++j) {
        const size_t row = rowBase + (wr << 6) + (m << 4) + (lg << 2) + j;
        float v = acc[m][n][j];
        if (EPI == 0) {
          v = v > 0.f ? v : v * slope;
          obf[row * ld_bf + col] = f2b(v);
        } else if (EPI == 1) {
          obf[row * ld_bf + col] = f2b(v);
          cs[n] += v; cq[n] += v * v;
        } else {
          of32[row * ld_f32 + col] = v;
          obf[row * ld_bf + col] = f2b(v);
        }
      }
    }
  }
  if (EPI == 1) {
#pragma unroll
    for (int n = 0; n < NF; ++n) {
      float s = cs[n], q = cq[n];
      s += __shfl_xor(s, 16); s += __shfl_xor(s, 32);
      q += __shfl_xor(q, 16); q += __shfl_xor(q, 32);
      if (lane < 16) {
        const int col = colBase + wc * CW + (n << 4) + lane;
        atomicAdd(&stats[col], s);
        atomicAdd(&stats[M + col], q);
      }
    }
  }
}

// ---------------- BN + leaky ----------------
__global__ __launch_bounds__(256) void k_bnact(const u16* __restrict__ pre, u16* __restrict__ act,
                                               const float* __restrict__ st, const float* __restrict__ g,
                                               const float* __restrict__ b, int M, float invB) {
  size_t idx = ((size_t)blockIdx.x * 256 + threadIdx.x) << 2;
  int c0 = (int)(idx & (size_t)(M - 1));
  ushort4 u = *(const ushort4*)(pre + idx);
  float vv[4] = {b2f(u.x), b2f(u.y), b2f(u.z), b2f(u.w)};
  u16 rr[4];
#pragma unroll
  for (int j = 0; j < 4; ++j) {
    int c = c0 + j;
    float mu = st[c] * invB;
    float var = st[M + c] * invB - mu * mu;
    float v = (vv[j] - mu) * rsqrtf(var + 1e-5f) * g[c] + b[c];
    rr[j] = f2b(lrelu(v, 0.01f));
  }
  ushort4 r; r.x = rr[0]; r.y = rr[1]; r.z = rr[2]; r.w = rr[3];
  *(ushort4*)(act + idx) = r;
}

__global__ __launch_bounds__(256) void k_fout(const u16* __restrict__ h, const float* __restrict__ W,
                                              float* __restrict__ out) {
  __shared__ float sw[128];
  if (threadIdx.x < 128) sw[threadIdx.x] = W[threadIdx.x];
  __syncthreads();
  int b = blockIdx.x * 256 + threadIdx.x;
  const u16* hp = h + (size_t)b * 128;
  float acc = 0.f;
#pragma unroll
  for (int k = 0; k < 128; k += 4) {
    ushort4 u = *(const ushort4*)(hp + k);
    acc += b2f(u.x) * sw[k] + b2f(u.y) * sw[k + 1] + b2f(u.z) * sw[k + 2] + b2f(u.w) * sw[k + 3];
  }
  out[b] = acc;
}

// ---------------- launch ----------------
extern "C" void kernel_launch(void* const* d_in, const int* in_sizes, int n_in,
                              void* d_out, int out_size, void* d_ws, size_t ws_size,
                              hipStream_t stream) {
  (void)in_sizes; (void)n_in; (void)out_size; (void)ws_size;

  const float* x[2] = {(const float*)d_in[0], (const float*)d_in[3]};
  const int* ei[2] = {(const int*)d_in[1], (const int*)d_in[4]};
  const float* ea[2] = {(const float*)d_in[2], (const float*)d_in[5]};
  const float* dm = (const float*)d_in[6];
  const float* nv = (const float*)d_in[7];
  const int* od = (const int*)d_in[8];
  const float* Wl[2] = {(const float*)d_in[9], (const float*)d_in[16]};
  const float* bl[2] = {(const float*)d_in[10], (const float*)d_in[17]};
  const float* Wr[2] = {(const float*)d_in[11], (const float*)d_in[18]};
  const float* br[2] = {(const float*)d_in[12], (const float*)d_in[19]};
  const float* We[2] = {(const float*)d_in[13], (const float*)d_in[20]};
  const float* att[2] = {(const float*)d_in[14], (const float*)d_in[21]};
  const float* bia[2] = {(const float*)d_in[15], (const float*)d_in[22]};
  const float* eW1 = (const float*)d_in[23];
  const float* eW2 = (const float*)d_in[24];
  const float* eW3 = (const float*)d_in[25];
  const float* eW4 = (const float*)d_in[26];
  const float* eWo = (const float*)d_in[27];
  const float* fW1 = (const float*)d_in[28];
  const float* fW2 = (const float*)d_in[29];
  const float* fW3 = (const float*)d_in[30];
  const float* fW4 = (const float*)d_in[31];
  const float* fWo = (const float*)d_in[32];
  const float* fg[4] = {(const float*)d_in[33], (const float*)d_in[35], (const float*)d_in[37], (const float*)d_in[39]};
  const float* fb[4] = {(const float*)d_in[34], (const float*)d_in[36], (const float*)d_in[38], (const float*)d_in[40]};

  float* out_inf = (float*)d_out;
  float* out_a1 = out_inf + NB;
  float* out_a2 = out_a1 + (size_t)ET * 4;
  float* out_evo = out_a2 + (size_t)ET * 4;

  // ---- workspace carve (~322 MB total) ----
  char* base = (char*)d_ws;
  size_t cur = 0;
  auto carve = [&](size_t bytes) -> char* {
    char* p = base + cur;
    cur += (bytes + 255) & ~(size_t)255;
    return p;
  };
  u16* bufA = (u16*)carve((size_t)NB * 256 * 2);
  u16* bufB = (u16*)carve((size_t)NB * 256 * 2);
  char* cluster = base + cur;  // cat (B x 96 bf16) aliases the scratch below (dead by then)
  float* n1 = (float*)carve((size_t)NN * 128 * 4);
  float* n2 = (float*)carve((size_t)NN * 128 * 4);
  float* Qo = (float*)carve((size_t)NN * 256 * 4);
  float* Qd = (float*)carve((size_t)NN * 256 * 4);
  float* xl = (float*)carve((size_t)NN * 128 * 4);
  float* xr = (float*)carve((size_t)NN * 128 * 4);
  const size_t gatBytes = (size_t)NN * 128 * 4 + NN * 4 + NN * 8 * 4 + NN * 4 * 4 + NN * 4 * 4;
  char* gatblk = carve(gatBytes);
  float* nacc = (float*)gatblk;
  float* deg = nacc + NN * 128;
  float* asum = deg + NN;
  u32* mxkey = (u32*)(asum + NN * 8);
  float* den = (float*)(mxkey + NN * 4);
  float* scr = (float*)carve((size_t)ET * 4 * 4);
  u16* cat = (u16*)cluster;
  float* distb = (float*)carve((size_t)NB * 4);
  float* w512 = (float*)carve(1024);
  float* stats = (float*)carve(1792 * 4);
  float* st[4] = {stats, stats + 512, stats + 1024, stats + 1536};
  u16* eW2b = (u16*)carve(256 * 256 * 2);
  u16* eW3b = (u16*)carve(256 * 256 * 2);
  u16* eW4b = (u16*)carve(128 * 256 * 2);
  u16* eWob = (u16*)carve(64 * 128 * 2);
  u16* fW1b = (u16*)carve(256 * 96 * 2);
  u16* fW2b = (u16*)carve(256 * 256 * 2);
  u16* fW3b = (u16*)carve(256 * 256 * 2);
  u16* fW4b = (u16*)carve(128 * 256 * 2);

  // ---- weight prep ----
  k_convw<<<256, 256, 0, stream>>>(eW2, eW2b, 256, 256, 256);
  k_convw<<<256, 256, 0, stream>>>(eW3, eW3b, 256, 256, 256);
  k_convw<<<128, 256, 0, stream>>>(eW4, eW4b, 128, 256, 256);
  k_convw<<<32, 256, 0, stream>>>(eWo, eWob, 64, 128, 128);
  k_convw<<<96, 256, 0, stream>>>(fW1, fW1b, 256, 69, 96);
  k_convw<<<256, 256, 0, stream>>>(fW2, fW2b, 256, 256, 256);
  k_convw<<<256, 256, 0, stream>>>(fW3, fW3b, 256, 256, 256);
  k_convw<<<128, 256, 0, stream>>>(fW4, fW4b, 128, 256, 256);
  k_w512<<<1, 256, 0, stream>>>(eW1, w512);
  hipMemsetAsync(stats, 0, 1792 * 4, stream);
  k_distb<<<NB / 256, 256, 0, stream>>>(od, dm, distb);

  // ---- GATv2 x2 ----
  float* nout[2] = {n1, n2};
  float* aout[2] = {out_a1, out_a2};
  for (int gi = 0; gi < 2; ++gi) {
    hipMemsetAsync(gatblk, 0, gatBytes, stream);
    k_deg<<<NE / 256, 256, 0, stream>>>(ei[gi], ea[gi], deg, asum);
    k_mean<<<(NN * 8 + 255) / 256, 256, 0, stream>>>(asum, deg);
    k_xlr<<<NN / 2, 256, 0, stream>>>(x[gi], Wl[gi], bl[gi], Wr[gi], br[gi], xl, xr);
    k_scr<<<ET / 2, 256, 0, stream>>>(xl, xr, ei[gi], ea[gi], asum, We[gi], att[gi], scr, mxkey);
    k_exden<<<(ET * 4 + 255) / 256, 256, 0, stream>>>(scr, ei[gi], mxkey, den);
    k_scatter<<<ET / 2, 256, 0, stream>>>(scr, den, ei[gi], xl, nacc, aout[gi]);
    k_nodeout<<<NN * 128 / 256, 256, 0, stream>>>(nacc, bia[gi], nout[gi]);
  }

  // ---- evo ----
  k_qtab<<<NN / 8, 256, 0, stream>>>(n1, n2, eW1, Qo, Qd);
  k_evo1<<<NB * 64 / 256, 256, 0, stream>>>(Qo, Qd, od, distb, w512, bufA);
  k_catx<<<NB / 256, 256, 0, stream>>>(od, nv, distb, cat);  // after evo1 (cat aliases Qo/Qd)

  dim3 g2(NB / 128, 2), g1(NB / 128, 1);
  const float invB = 1.0f / (float)NB;
  gemm_bf16<4, 0><<<g2, 256, 0, stream>>>(bufA, eW2b, 256, 256, bufB, 256, nullptr, 0, nullptr, 0.01f);
  gemm_bf16<4, 0><<<g2, 256, 0, stream>>>(bufB, eW3b, 256, 256, bufA, 256, nullptr, 0, nullptr, 0.01f);
  gemm_bf16<4, 0><<<g1, 256, 0, stream>>>(bufA, eW4b, 256, 128, bufB, 128, nullptr, 0, nullptr, 0.01f);
  gemm_bf16<2, 2><<<g1, 256, 0, stream>>>(bufB, eWob, 128, 64, cat, 96, out_evo, 64, nullptr, 0.f);

  // ---- flow ----
  gemm_bf16<4, 1><<<g2, 256, 0, stream>>>(cat, fW1b, 96, 256, bufA, 256, nullptr, 0, st[0], 0.f);
  k_bnact<<<NB * 256 / 4 / 256, 256, 0, stream>>>(bufA, bufB, st[0], fg[0], fb[0], 256, invB);
  gemm_bf16<4, 1><<<g2, 256, 0, stream>>>(bufB, fW2b, 256, 256, bufA, 256, nullptr, 0, st[1], 0.f);
  k_bnact<<<NB * 256 / 4 / 256, 256, 0, stream>>>(bufA, bufB, st[1], fg[1], fb[1], 256, invB);
  gemm_bf16<4, 1><<<g2, 256, 0, stream>>>(bufB, fW3b, 256, 256, bufA, 256, nullptr, 0, st[2], 0.f);
  k_bnact<<<NB * 256 / 4 / 256, 256, 0, stream>>>(bufA, bufB, st[2], fg[2], fb[2], 256, invB);
  gemm_bf16<4, 1><<<g1, 256, 0, stream>>>(bufB, fW4b, 256, 128, bufA, 128, nullptr, 0, st[3], 0.f);
  k_bnact<<<NB * 128 / 4 / 256, 256, 0, stream>>>(bufA, bufB, st[3], fg[3], fb[3], 128, invB);
  k_fout<<<NB / 256, 256, 0, stream>>>(bufB, fWo, out_inf);
}

// Round 2
// 2388.960 us; speedup vs baseline: 1.1862x; 1.1862x over previous
//
#include <hip/hip_runtime.h>

typedef unsigned short u16;
typedef unsigned int u32;

#define NN 10000      // nodes
#define NE 320000     // edges
#define ET 330000     // edges + self loops
#define NB 262144     // batch

typedef __attribute__((ext_vector_type(8))) short bf16x8;
typedef __attribute__((ext_vector_type(4))) float f32x4;

__device__ __forceinline__ u16 f2b(float f) {
  u32 u = __float_as_uint(f);
  u += 0x7fffu + ((u >> 16) & 1u);
  return (u16)(u >> 16);
}
__device__ __forceinline__ float b2f(u16 h) {
  return __uint_as_float(((u32)h) << 16);
}
__device__ __forceinline__ u32 fkey(float f) {
  u32 u = __float_as_uint(f);
  return (u & 0x80000000u) ? ~u : (u | 0x80000000u);
}
__device__ __forceinline__ float fdecode(u32 k) {
  return __uint_as_float((k & 0x80000000u) ? (k & 0x7fffffffu) : ~k);
}
__device__ __forceinline__ float lrelu(float v, float s) { return v > 0.f ? v : v * s; }

__device__ __forceinline__ void g2lds16(const void* g, void* l) {
  __builtin_amdgcn_global_load_lds((const __attribute__((address_space(1))) void*)g,
                                   (__attribute__((address_space(3))) void*)l, 16, 0, 0);
}

// ---------------- weight conversion ----------------
__global__ __launch_bounds__(256) void k_convw(const float* __restrict__ src, u16* __restrict__ dst,
                                               int M, int Ks, int Kd) {
  int t = blockIdx.x * 256 + threadIdx.x;
  if (t >= M * Kd) return;
  int m = t / Kd, k = t - m * Kd;
  float v = (k < Ks) ? src[(size_t)m * Ks + k] : 0.f;
  dst[t] = f2b(v);
}

__global__ void k_w512(const float* __restrict__ W1, float* __restrict__ w512) {
  w512[threadIdx.x] = W1[(size_t)threadIdx.x * 513 + 512];
}

// transpose evo W1 (256 x 513) -> W1T (512 x 256), k-major
__global__ __launch_bounds__(256) void k_trw1(const float* __restrict__ W1, float* __restrict__ W1T) {
  int m = blockIdx.x;  // 256
  for (int k = threadIdx.x; k < 512; k += 256)
    W1T[(size_t)k * 256 + m] = W1[(size_t)m * 513 + k];
}

// ---------------- GAT ----------------
__global__ __launch_bounds__(256) void k_deg(const int* __restrict__ ei, const float* __restrict__ ea,
                                             float* __restrict__ deg, float* __restrict__ asum) {
  int t = blockIdx.x * 256 + threadIdx.x;
  if (t >= NE) return;
  int d = ei[NE + t];
  atomicAdd(&deg[d], 1.f);
  const float* e = ea + (size_t)t * 8;
  float* as = asum + (size_t)d * 8;
#pragma unroll
  for (int j = 0; j < 8; ++j) atomicAdd(&as[j], e[j]);
}

__global__ __launch_bounds__(256) void k_mean(float* __restrict__ asum, const float* __restrict__ deg) {
  int t = blockIdx.x * 256 + threadIdx.x;
  if (t >= NN * 8) return;
  asum[t] /= fmaxf(deg[t >> 3], 1.f);
}

__global__ __launch_bounds__(256) void k_xlr(const float* __restrict__ x,
                                             const float* __restrict__ Wl, const float* __restrict__ bl,
                                             const float* __restrict__ Wr, const float* __restrict__ br,
                                             float* __restrict__ xl, float* __restrict__ xr) {
  __shared__ float sx[128];
  int nb = blockIdx.x * 2;
  for (int i = threadIdx.x; i < 128; i += 256) sx[i] = x[(size_t)nb * 64 + i];
  __syncthreads();
  int half = threadIdx.x >> 7;
  int node = nb + half;
  int m = threadIdx.x & 127;
  const float* xv = sx + (half << 6);
  float al = bl[m], ar = br[m];
  const float* wl = Wl + (size_t)m * 64;
  const float* wr = Wr + (size_t)m * 64;
#pragma unroll 8
  for (int k = 0; k < 64; ++k) { float xk = xv[k]; al += xk * wl[k]; ar += xk * wr[k]; }
  xl[(size_t)node * 128 + m] = al;
  xr[(size_t)node * 128 + m] = ar;
}

__global__ __launch_bounds__(256) void k_scr(const float* __restrict__ xl, const float* __restrict__ xr,
                                             const int* __restrict__ ei, const float* __restrict__ ea,
                                             const float* __restrict__ mattr,
                                             const float* __restrict__ We, const float* __restrict__ att,
                                             float* __restrict__ scr, u32* __restrict__ mxkey) {
  __shared__ float sWeT[8 * 128];
  __shared__ float sAtt[128];
  for (int i = threadIdx.x; i < 1024; i += 256) sWeT[(i & 7) * 128 + (i >> 3)] = We[i];
  if (threadIdx.x < 128) sAtt[threadIdx.x] = att[threadIdx.x];
  __syncthreads();
  int t = blockIdx.x * 256 + threadIdx.x;
  int e = t >> 7, hc = t & 127;
  int s, d; const float* ap;
  if (e < NE) { s = ei[e]; d = ei[NE + e]; ap = ea + (size_t)e * 8; }
  else { s = e - NE; d = s; ap = mattr + (size_t)(e - NE) * 8; }
  float em = 0.f;
#pragma unroll
  for (int j = 0; j < 8; ++j) em += ap[j] * sWeT[j * 128 + hc];
  float v = xl[(size_t)s * 128 + hc] + xr[(size_t)d * 128 + hc] + em;
  v = v > 0.f ? v : 0.2f * v;
  float p = v * sAtt[hc];
#pragma unroll
  for (int off = 16; off; off >>= 1) p += __shfl_xor(p, off);
  if ((hc & 31) == 0) {
    int h = hc >> 5;
    scr[(size_t)e * 4 + h] = p;
    atomicMax(&mxkey[d * 4 + h], fkey(p));
  }
}

__global__ __launch_bounds__(256) void k_exden(float* __restrict__ scr, const int* __restrict__ ei,
                                               const u32* __restrict__ mxkey, float* __restrict__ den) {
  int t = blockIdx.x * 256 + threadIdx.x;
  if (t >= ET * 4) return;
  int e = t >> 2, h = t & 3;
  int d = (e < NE) ? ei[NE + e] : (e - NE);
  float mx = fdecode(mxkey[d * 4 + h]);
  float ex = expf(scr[t] - mx);
  scr[t] = ex;
  atomicAdd(&den[d * 4 + h], ex);
}

__global__ __launch_bounds__(256) void k_scatter(const float* __restrict__ scr, const float* __restrict__ den,
                                                 const int* __restrict__ ei, const float* __restrict__ xl,
                                                 float* __restrict__ nacc, float* __restrict__ aout) {
  int t = blockIdx.x * 256 + threadIdx.x;
  int e = t >> 7, hc = t & 127, h = hc >> 5;
  int s, d;
  if (e < NE) { s = ei[e]; d = ei[NE + e]; }
  else { s = e - NE; d = s; }
  float a = scr[(size_t)e * 4 + h] / den[d * 4 + h];
  if ((hc & 31) == 0) aout[(size_t)e * 4 + h] = a;
  atomicAdd(&nacc[(size_t)d * 128 + hc], a * xl[(size_t)s * 128 + hc]);
}

__global__ __launch_bounds__(256) void k_nodeout(const float* __restrict__ nacc,
                                                 const float* __restrict__ bias,
                                                 float* __restrict__ nout) {
  int t = blockIdx.x * 256 + threadIdx.x;  // NN*128 exact
  int hc = t & 127;
  nout[t] = fmaxf(nacc[t] + bias[hc], 0.f);
}

// ---------------- evo L1 factorization ----------------
// Qo/Qd node tables via coalesced k-major W1T reads; 16 nodes per block.
__global__ __launch_bounds__(256) void k_qtab(const float* __restrict__ n1, const float* __restrict__ n2,
                                              const float* __restrict__ W1T,
                                              float* __restrict__ Qo, float* __restrict__ Qd) {
  __shared__ float s1[2048], s2[2048];
  int nb = blockIdx.x * 16;
  for (int i = threadIdx.x; i < 2048; i += 256) {
    s1[i] = n1[(size_t)nb * 128 + i];
    s2[i] = n2[(size_t)nb * 128 + i];
  }
  __syncthreads();
  int m = threadIdx.x;
  float qo[16], qd[16];
#pragma unroll
  for (int i = 0; i < 16; ++i) { qo[i] = 0.f; qd[i] = 0.f; }
#pragma unroll 2
  for (int k = 0; k < 128; ++k) {
    float w0 = W1T[(size_t)k * 256 + m];
    float w1 = W1T[(size_t)(128 + k) * 256 + m];
    float w2 = W1T[(size_t)(256 + k) * 256 + m];
    float w3 = W1T[(size_t)(384 + k) * 256 + m];
#pragma unroll
    for (int i = 0; i < 16; ++i) {
      float a = s1[i * 128 + k], b = s2[i * 128 + k];
      qo[i] += a * w0 + b * w2;
      qd[i] += a * w1 + b * w3;
    }
  }
#pragma unroll
  for (int i = 0; i < 16; ++i) {
    Qo[(size_t)(nb + i) * 256 + m] = qo[i];
    Qd[(size_t)(nb + i) * 256 + m] = qd[i];
  }
}

__global__ __launch_bounds__(256) void k_distb(const int* __restrict__ od, const float* __restrict__ dm,
                                               float* __restrict__ distb) {
  int t = blockIdx.x * 256 + threadIdx.x;
  int o = od[t * 2], d = od[t * 2 + 1];
  distb[t] = dm[(size_t)o * NN + d];
}

__global__ __launch_bounds__(256) void k_evo1(const float* __restrict__ Qo, const float* __restrict__ Qd,
                                              const int* __restrict__ od, const float* __restrict__ distb,
                                              const float* __restrict__ w512, u16* __restrict__ h1) {
  __shared__ float sw[256];
  sw[threadIdx.x] = w512[threadIdx.x];
  __syncthreads();
  int t = blockIdx.x * 256 + threadIdx.x;
  int b = t >> 6, mq = (t & 63) << 2;
  int o = od[b * 2], d = od[b * 2 + 1];
  float dist = distb[b];
  const float4 qa = *(const float4*)(Qo + (size_t)o * 256 + mq);
  const float4 qc = *(const float4*)(Qd + (size_t)d * 256 + mq);
  float v0 = qa.x + qc.x + dist * sw[mq + 0];
  float v1 = qa.y + qc.y + dist * sw[mq + 1];
  float v2 = qa.z + qc.z + dist * sw[mq + 2];
  float v3 = qa.w + qc.w + dist * sw[mq + 3];
  ushort4 r;
  r.x = f2b(lrelu(v0, 0.01f)); r.y = f2b(lrelu(v1, 0.01f));
  r.z = f2b(lrelu(v2, 0.01f)); r.w = f2b(lrelu(v3, 0.01f));
  *(ushort4*)(h1 + (size_t)b * 256 + mq) = r;
}

__global__ __launch_bounds__(256) void k_catx(const int* __restrict__ od, const float* __restrict__ nv,
                                              const float* __restrict__ distb, u16* __restrict__ cat) {
  int b = blockIdx.x * 256 + threadIdx.x;
  int o = od[b * 2], d = od[b * 2 + 1];
  u16* c = cat + (size_t)b * 96 + 64;
  c[0] = f2b(nv[o * 2]);
  c[1] = f2b(nv[d * 2]);
  c[2] = f2b(nv[o * 2 + 1]);
  c[3] = f2b(nv[d * 2 + 1]);
  c[4] = f2b(distb[b]);
#pragma unroll
  for (int k = 5; k < 32; ++k) c[k] = 0;
}

// ---------------- MFMA GEMM: C = A(B x K) @ W(M x K)^T ----------------
// EPI: 0 = leaky->bf16, 1 = raw bf16 + column stats (sum,sumsq), 2 = f32 + bf16 raw
// COLS: grid-y columns of 128; COLS==2 uses a 1D grid with XCD-pair swizzle so the
// two blocks sharing an A-panel land on the same XCD, 8 dispatches apart.
template <int NF, int EPI, int COLS>
__global__ __launch_bounds__(256) void gemm_bf16(const u16* __restrict__ A, const u16* __restrict__ W,
                                                 int K, int M,
                                                 u16* __restrict__ obf, int ld_bf,
                                                 float* __restrict__ of32, int ld_f32,
                                                 float* __restrict__ stats, float slope) {
  constexpr int CW = NF * 16;   // cols per wave
  constexpr int BN = CW * 2;    // block cols
  __shared__ u16 Alds[128 * 32];
  __shared__ u16 Blds[BN * 32];
  const int lane = threadIdx.x & 63;
  const int w = threadIdx.x >> 6;
  const int wr = w >> 1, wc = w & 1;
  int bx, by;
  if (COLS == 2) {
    const int id = blockIdx.x;          // 0..(2*gridX)-1
    const int g = id >> 4, t = id & 15;
    by = t >> 3;
    bx = (g << 3) + (t & 7);
  } else {
    bx = blockIdx.x; by = 0;
  }
  const size_t rowBase = (size_t)bx * 128;
  const int colBase = by * BN;

  f32x4 acc[4][NF];
  const f32x4 z4 = {0.f, 0.f, 0.f, 0.f};
#pragma unroll
  for (int m = 0; m < 4; ++m)
#pragma unroll
    for (int n = 0; n < NF; ++n) acc[m][n] = z4;

  const int sr = (w << 4) + (lane >> 2);   // staging row within 64-row group
  const int sc = (lane & 3) << 3;          // staging col (elems)
  const int KT = K >> 5;
  for (int kt = 0; kt < KT; ++kt) {
    const int kb = kt << 5;
#pragma unroll
    for (int i = 0; i < 2; ++i) {
      const u16* src = A + (rowBase + (i << 6) + sr) * (size_t)K + kb + sc;
      g2lds16(src, &Alds[((i << 6) + (w << 4)) << 5]);
    }
#pragma unroll
    for (int i = 0; i < NF / 2; ++i) {
      const u16* src = W + (size_t)(colBase + (i << 6) + sr) * K + kb + sc;
      g2lds16(src, &Blds[((i << 6) + (w << 4)) << 5]);
    }
    __syncthreads();
    const int lr = lane & 15, lk = (lane >> 4) << 3;
    bf16x8 af[4], bfr[NF];
#pragma unroll
    for (int m = 0; m < 4; ++m)
      af[m] = *(const bf16x8*)&Alds[(((wr << 6) + (m << 4) + lr) << 5) + lk];
#pragma unroll
    for (int n = 0; n < NF; ++n)
      bfr[n] = *(const bf16x8*)&Blds[((wc * CW + (n << 4) + lr) << 5) + lk];
#pragma unroll
    for (int m = 0; m < 4; ++m)
#pragma unroll
      for (int n = 0; n < NF; ++n)
        acc[m][n] = __builtin_amdgcn_mfma_f32_16x16x32_bf16(af[m], bfr[n], acc[m][n], 0, 0, 0);
    __syncthreads();
  }

  const int lr = lane & 15, lg = lane >> 4;
  float cs[NF], cq[NF];
#pragma unroll
  for (int n = 0; n < NF; ++n) { cs[n] = 0.f; cq[n] = 0.f; }
#pragma unroll
  for (int m = 0; m < 4; ++m) {
#pragma unroll
    for (int n = 0; n < NF; ++n) {
      const int col = colBase + wc * CW + (n << 4) + lr;
#pragma unroll
      for (int j = 0; j < 4; ++j) {
        const size_t row = rowBase + (wr << 6) + (m << 4) + (lg << 2) + j;
        float v = acc[m][n][j];
        if (EPI == 0) {
          v = v > 0.f ? v : v * slope;
          obf[row * ld_bf + col] = f2b(v);
        } else if (EPI == 1) {
          obf[row * ld_bf + col] = f2b(v);
          cs[n] += v; cq[n] += v * v;
        } else {
          of32[row * ld_f32 + col] = v;
          obf[row * ld_bf + col] = f2b(v);
        }
      }
    }
  }
  if (EPI == 1) {
#pragma unroll
    for (int n = 0; n < NF; ++n) {
      float s = cs[n], q = cq[n];
      s += __shfl_xor(s, 16); s += __shfl_xor(s, 32);
      q += __shfl_xor(q, 16); q += __shfl_xor(q, 32);
      if (lane < 16) {
        const int col = colBase + wc * CW + (n << 4) + lane;
        atomicAdd(&stats[col], s);
        atomicAdd(&stats[M + col], q);
      }
    }
  }
}

// ---------------- BN + leaky (16B/lane) ----------------
__global__ __launch_bounds__(256) void k_bnact(const u16* __restrict__ pre, u16* __restrict__ act,
                                               const float* __restrict__ st, const float* __restrict__ g,
                                               const float* __restrict__ b, int M, float invB) {
  size_t idx = ((size_t)blockIdx.x * 256 + threadIdx.x) << 3;
  int c0 = (int)(idx & (size_t)(M - 1));
  bf16x8 u = *(const bf16x8*)(pre + idx);
  u16 rr[8];
#pragma unroll
  for (int j = 0; j < 8; ++j) {
    int c = c0 + j;
    float mu = st[c] * invB;
    float var = st[M + c] * invB - mu * mu;
    float v = (b2f((u16)u[j]) - mu) * rsqrtf(var + 1e-5f) * g[c] + b[c];
    rr[j] = f2b(lrelu(v, 0.01f));
  }
  bf16x8 r;
#pragma unroll
  for (int j = 0; j < 8; ++j) r[j] = (short)rr[j];
  *(bf16x8*)(act + idx) = r;
}

__global__ __launch_bounds__(256) void k_fout(const u16* __restrict__ h, const float* __restrict__ W,
                                              float* __restrict__ out) {
  __shared__ float sw[128];
  if (threadIdx.x < 128) sw[threadIdx.x] = W[threadIdx.x];
  __syncthreads();
  int b = blockIdx.x * 256 + threadIdx.x;
  const u16* hp = h + (size_t)b * 128;
  float acc = 0.f;
#pragma unroll
  for (int k = 0; k < 128; k += 4) {
    ushort4 u = *(const ushort4*)(hp + k);
    acc += b2f(u.x) * sw[k] + b2f(u.y) * sw[k + 1] + b2f(u.z) * sw[k + 2] + b2f(u.w) * sw[k + 3];
  }
  out[b] = acc;
}

// ---------------- launch ----------------
extern "C" void kernel_launch(void* const* d_in, const int* in_sizes, int n_in,
                              void* d_out, int out_size, void* d_ws, size_t ws_size,
                              hipStream_t stream) {
  (void)in_sizes; (void)n_in; (void)out_size; (void)ws_size;

  const float* x[2] = {(const float*)d_in[0], (const float*)d_in[3]};
  const int* ei[2] = {(const int*)d_in[1], (const int*)d_in[4]};
  const float* ea[2] = {(const float*)d_in[2], (const float*)d_in[5]};
  const float* dm = (const float*)d_in[6];
  const float* nv = (const float*)d_in[7];
  const int* od = (const int*)d_in[8];
  const float* Wl[2] = {(const float*)d_in[9], (const float*)d_in[16]};
  const float* bl[2] = {(const float*)d_in[10], (const float*)d_in[17]};
  const float* Wr[2] = {(const float*)d_in[11], (const float*)d_in[18]};
  const float* br[2] = {(const float*)d_in[12], (const float*)d_in[19]};
  const float* We[2] = {(const float*)d_in[13], (const float*)d_in[20]};
  const float* att[2] = {(const float*)d_in[14], (const float*)d_in[21]};
  const float* bia[2] = {(const float*)d_in[15], (const float*)d_in[22]};
  const float* eW1 = (const float*)d_in[23];
  const float* eW2 = (const float*)d_in[24];
  const float* eW3 = (const float*)d_in[25];
  const float* eW4 = (const float*)d_in[26];
  const float* eWo = (const float*)d_in[27];
  const float* fW1 = (const float*)d_in[28];
  const float* fW2 = (const float*)d_in[29];
  const float* fW3 = (const float*)d_in[30];
  const float* fW4 = (const float*)d_in[31];
  const float* fWo = (const float*)d_in[32];
  const float* fg[4] = {(const float*)d_in[33], (const float*)d_in[35], (const float*)d_in[37], (const float*)d_in[39]};
  const float* fb[4] = {(const float*)d_in[34], (const float*)d_in[36], (const float*)d_in[38], (const float*)d_in[40]};

  float* out_inf = (float*)d_out;
  float* out_a1 = out_inf + NB;
  float* out_a2 = out_a1 + (size_t)ET * 4;
  float* out_evo = out_a2 + (size_t)ET * 4;

  // ---- workspace carve (~322 MB total) ----
  char* base = (char*)d_ws;
  size_t cur = 0;
  auto carve = [&](size_t bytes) -> char* {
    char* p = base + cur;
    cur += (bytes + 255) & ~(size_t)255;
    return p;
  };
  u16* bufA = (u16*)carve((size_t)NB * 256 * 2);
  u16* bufB = (u16*)carve((size_t)NB * 256 * 2);
  char* cluster = base + cur;  // cat (B x 96 bf16) aliases the scratch below (dead by then)
  float* n1 = (float*)carve((size_t)NN * 128 * 4);
  float* n2 = (float*)carve((size_t)NN * 128 * 4);
  float* Qo = (float*)carve((size_t)NN * 256 * 4);
  float* Qd = (float*)carve((size_t)NN * 256 * 4);
  float* xl = (float*)carve((size_t)NN * 128 * 4);
  float* xr = (float*)carve((size_t)NN * 128 * 4);
  const size_t gatBytes = (size_t)NN * 128 * 4 + NN * 4 + NN * 8 * 4 + NN * 4 * 4 + NN * 4 * 4;
  char* gatblk = carve(gatBytes);
  float* nacc = (float*)gatblk;
  float* deg = nacc + NN * 128;
  float* asum = deg + NN;
  u32* mxkey = (u32*)(asum + NN * 8);
  float* den = (float*)(mxkey + NN * 4);
  float* scr = (float*)carve((size_t)ET * 4 * 4);
  u16* cat = (u16*)cluster;
  // --- below here is NOT aliased by cat ---
  float* distb = (float*)carve((size_t)NB * 4);
  float* w512 = (float*)carve(1024);
  float* W1T = (float*)carve(512 * 256 * 4);
  float* stats = (float*)carve(1792 * 4);
  float* st[4] = {stats, stats + 512, stats + 1024, stats + 1536};
  u16* eW2b = (u16*)carve(256 * 256 * 2);
  u16* eW3b = (u16*)carve(256 * 256 * 2);
  u16* eW4b = (u16*)carve(128 * 256 * 2);
  u16* eWob = (u16*)carve(64 * 128 * 2);
  u16* fW1b = (u16*)carve(256 * 96 * 2);
  u16* fW2b = (u16*)carve(256 * 256 * 2);
  u16* fW3b = (u16*)carve(256 * 256 * 2);
  u16* fW4b = (u16*)carve(128 * 256 * 2);

  // ---- weight prep ----
  k_convw<<<256, 256, 0, stream>>>(eW2, eW2b, 256, 256, 256);
  k_convw<<<256, 256, 0, stream>>>(eW3, eW3b, 256, 256, 256);
  k_convw<<<128, 256, 0, stream>>>(eW4, eW4b, 128, 256, 256);
  k_convw<<<32, 256, 0, stream>>>(eWo, eWob, 64, 128, 128);
  k_convw<<<96, 256, 0, stream>>>(fW1, fW1b, 256, 69, 96);
  k_convw<<<256, 256, 0, stream>>>(fW2, fW2b, 256, 256, 256);
  k_convw<<<256, 256, 0, stream>>>(fW3, fW3b, 256, 256, 256);
  k_convw<<<128, 256, 0, stream>>>(fW4, fW4b, 128, 256, 256);
  k_w512<<<1, 256, 0, stream>>>(eW1, w512);
  k_trw1<<<256, 256, 0, stream>>>(eW1, W1T);
  hipMemsetAsync(stats, 0, 1792 * 4, stream);
  k_distb<<<NB / 256, 256, 0, stream>>>(od, dm, distb);

  // ---- GATv2 x2 ----
  float* nout[2] = {n1, n2};
  float* aout[2] = {out_a1, out_a2};
  for (int gi = 0; gi < 2; ++gi) {
    hipMemsetAsync(gatblk, 0, gatBytes, stream);
    k_deg<<<NE / 256, 256, 0, stream>>>(ei[gi], ea[gi], deg, asum);
    k_mean<<<(NN * 8 + 255) / 256, 256, 0, stream>>>(asum, deg);
    k_xlr<<<NN / 2, 256, 0, stream>>>(x[gi], Wl[gi], bl[gi], Wr[gi], br[gi], xl, xr);
    k_scr<<<ET / 2, 256, 0, stream>>>(xl, xr, ei[gi], ea[gi], asum, We[gi], att[gi], scr, mxkey);
    k_exden<<<(ET * 4 + 255) / 256, 256, 0, stream>>>(scr, ei[gi], mxkey, den);
    k_scatter<<<ET / 2, 256, 0, stream>>>(scr, den, ei[gi], xl, nacc, aout[gi]);
    k_nodeout<<<NN * 128 / 256, 256, 0, stream>>>(nacc, bia[gi], nout[gi]);
  }

  // ---- evo ----
  k_qtab<<<NN / 16, 256, 0, stream>>>(n1, n2, W1T, Qo, Qd);
  k_evo1<<<NB * 64 / 256, 256, 0, stream>>>(Qo, Qd, od, distb, w512, bufA);
  k_catx<<<NB / 256, 256, 0, stream>>>(od, nv, distb, cat);  // after evo1 (cat aliases Qo/Qd)

  const float invB = 1.0f / (float)NB;
  const int G2 = NB / 128 * 2, G1 = NB / 128;
  gemm_bf16<4, 0, 2><<<G2, 256, 0, stream>>>(bufA, eW2b, 256, 256, bufB, 256, nullptr, 0, nullptr, 0.01f);
  gemm_bf16<4, 0, 2><<<G2, 256, 0, stream>>>(bufB, eW3b, 256, 256, bufA, 256, nullptr, 0, nullptr, 0.01f);
  gemm_bf16<4, 0, 1><<<G1, 256, 0, stream>>>(bufA, eW4b, 256, 128, bufB, 128, nullptr, 0, nullptr, 0.01f);
  gemm_bf16<2, 2, 1><<<G1, 256, 0, stream>>>(bufB, eWob, 128, 64, cat, 96, out_evo, 64, nullptr, 0.f);

  // ---- flow ----
  gemm_bf16<4, 1, 2><<<G2, 256, 0, stream>>>(cat, fW1b, 96, 256, bufA, 256, nullptr, 0, st[0], 0.f);
  k_bnact<<<NB * 256 / 8 / 256, 256, 0, stream>>>(bufA, bufB, st[0], fg[0], fb[0], 256, invB);
  gemm_bf16<4, 1, 2><<<G2, 256, 0, stream>>>(bufB, fW2b, 256, 256, bufA, 256, nullptr, 0, st[1], 0.f);
  k_bnact<<<NB * 256 / 8 / 256, 256, 0, stream>>>(bufA, bufB, st[1], fg[1], fb[1], 256, invB);
  gemm_bf16<4, 1, 2><<<G2, 256, 0, stream>>>(bufB, fW3b, 256, 256, bufA, 256, nullptr, 0, st[2], 0.f);
  k_bnact<<<NB * 256 / 8 / 256, 256, 0, stream>>>(bufA, bufB, st[2], fg[2], fb[2], 256, invB);
  gemm_bf16<4, 1, 1><<<G1, 256, 0, stream>>>(bufB, fW4b, 256, 128, bufA, 128, nullptr, 0, st[3], 0.f);
  k_bnact<<<NB * 128 / 8 / 256, 256, 0, stream>>>(bufA, bufB, st[3], fg[3], fb[3], 128, invB);
  k_fout<<<NB / 256, 256, 0, stream>>>(bufB, fWo, out_inf);
}

// Round 3
// 1669.279 us; speedup vs baseline: 1.6976x; 1.4311x over previous
//
#include <hip/hip_runtime.h>

typedef unsigned short u16;
typedef unsigned int u32;

#define NN 10000      // nodes
#define NE 320000     // edges
#define ET 330000     // edges + self loops
#define NB 262144     // batch

typedef __attribute__((ext_vector_type(8))) short bf16x8;
typedef __attribute__((ext_vector_type(4))) float f32x4;

__device__ __forceinline__ u16 f2b(float f) {
  u32 u = __float_as_uint(f);
  u += 0x7fffu + ((u >> 16) & 1u);
  return (u16)(u >> 16);
}
__device__ __forceinline__ float b2f(u16 h) {
  return __uint_as_float(((u32)h) << 16);
}
__device__ __forceinline__ float lrelu(float v, float s) { return v > 0.f ? v : v * s; }

__device__ __forceinline__ void g2lds16(const void* g, void* l) {
  __builtin_amdgcn_global_load_lds((const __attribute__((address_space(1))) void*)g,
                                   (__attribute__((address_space(3))) void*)l, 16, 0, 0);
}

// ---------------- weight conversion ----------------
__global__ __launch_bounds__(256) void k_convw(const float* __restrict__ src, u16* __restrict__ dst,
                                               int M, int Ks, int Kd) {
  int t = blockIdx.x * 256 + threadIdx.x;
  if (t >= M * Kd) return;
  int m = t / Kd, k = t - m * Kd;
  float v = (k < Ks) ? src[(size_t)m * Ks + k] : 0.f;
  dst[t] = f2b(v);
}

__global__ void k_w512(const float* __restrict__ W1, float* __restrict__ w512) {
  w512[threadIdx.x] = W1[(size_t)threadIdx.x * 513 + 512];
}

// transpose evo W1 (256 x 513) -> W1T (512 x 256), k-major
__global__ __launch_bounds__(256) void k_trw1(const float* __restrict__ W1, float* __restrict__ W1T) {
  int m = blockIdx.x;  // 256
  for (int k = threadIdx.x; k < 512; k += 256)
    W1T[(size_t)k * 256 + m] = W1[(size_t)m * 513 + k];
}

// ---------------- CSR build (per graph) ----------------
__global__ __launch_bounds__(256) void k_count(const int* __restrict__ ei, int* __restrict__ cnt) {
  int t = blockIdx.x * 256 + threadIdx.x;
  if (t >= ET) return;
  int d = (t < NE) ? ei[NE + t] : (t - NE);
  atomicAdd(&cnt[d], 1);
}

__global__ __launch_bounds__(1024) void k_scan(const int* __restrict__ cnt, int* __restrict__ cs) {
  __shared__ int part[1024];
  int tid = threadIdx.x;
  int base = tid * 10;
  int local[10];
  int s = 0;
#pragma unroll
  for (int i = 0; i < 10; ++i) {
    int idx = base + i;
    int v = (idx < NN) ? cnt[idx] : 0;
    local[i] = s; s += v;
  }
  part[tid] = s;
  __syncthreads();
  for (int off = 1; off < 1024; off <<= 1) {
    int v = (tid >= off) ? part[tid - off] : 0;
    __syncthreads();
    part[tid] += v;
    __syncthreads();
  }
  int pre = (tid > 0) ? part[tid - 1] : 0;
#pragma unroll
  for (int i = 0; i < 10; ++i) {
    int idx = base + i;
    if (idx < NN) cs[idx] = pre + local[i];
  }
  if (tid == 1023) cs[NN] = part[1023];
}

__global__ __launch_bounds__(256) void k_fill(const int* __restrict__ ei, const int* __restrict__ cs,
                                              int* __restrict__ wr, int2* __restrict__ csr) {
  int t = blockIdx.x * 256 + threadIdx.x;
  if (t >= ET) return;
  int s, d;
  if (t < NE) { s = ei[t]; d = ei[NE + t]; } else { s = t - NE; d = s; }
  int pos = atomicAdd(&wr[d], 1);
  csr[cs[d] + pos] = make_int2(t, s);
}

// mean edge attr per node (real edges only), via CSR gather
__global__ __launch_bounds__(256) void k_asum(const int2* __restrict__ csr, const int* __restrict__ cs,
                                              const float* __restrict__ ea, float* __restrict__ asum) {
  int wid = (blockIdx.x * 256 + threadIdx.x) >> 6;
  int lane = threadIdx.x & 63;
  int beg = cs[wid], end = cs[wid + 1];
  int j = lane & 7, slot = lane >> 3;
  float acc = 0.f;
  for (int i = beg + slot; i < end; i += 8) {
    int e = csr[i].x;
    if (e < NE) acc += ea[(size_t)e * 8 + j];
  }
  acc += __shfl_xor(acc, 8);
  acc += __shfl_xor(acc, 16);
  acc += __shfl_xor(acc, 32);
  if (lane < 8) {
    float dr = (float)(end - beg - 1);
    asum[(size_t)wid * 8 + lane] = acc / fmaxf(dr, 1.f);
  }
}

// ---------------- GAT ----------------
__global__ __launch_bounds__(256) void k_xlr(const float* __restrict__ x,
                                             const float* __restrict__ Wl, const float* __restrict__ bl,
                                             const float* __restrict__ Wr, const float* __restrict__ br,
                                             float* __restrict__ xl, float* __restrict__ xr) {
  __shared__ float sx[128];
  int nb = blockIdx.x * 2;
  for (int i = threadIdx.x; i < 128; i += 256) sx[i] = x[(size_t)nb * 64 + i];
  __syncthreads();
  int half = threadIdx.x >> 7;
  int node = nb + half;
  int m = threadIdx.x & 127;
  const float* xv = sx + (half << 6);
  float al = bl[m], ar = br[m];
  const float* wl = Wl + (size_t)m * 64;
  const float* wr = Wr + (size_t)m * 64;
#pragma unroll 8
  for (int k = 0; k < 64; ++k) { float xk = xv[k]; al += xk * wl[k]; ar += xk * wr[k]; }
  xl[(size_t)node * 128 + m] = al;
  xr[(size_t)node * 128 + m] = ar;
}

// scores: 32 lanes per edge, We/att cached in registers, grid-stride
__global__ __launch_bounds__(256) void k_scr(const float* __restrict__ xl, const float* __restrict__ xr,
                                             const int* __restrict__ ei, const float* __restrict__ ea,
                                             const float* __restrict__ mattr,
                                             const float* __restrict__ We, const float* __restrict__ att,
                                             float* __restrict__ scr) {
  const int lane = threadIdx.x & 63;
  const int sub = lane & 31;
  const int half = lane >> 5;
  float4 w0[4], w1[4];
#pragma unroll
  for (int c = 0; c < 4; ++c) {
    const float* wp = We + (size_t)(sub * 4 + c) * 8;
    w0[c] = *(const float4*)wp;
    w1[c] = *(const float4*)(wp + 4);
  }
  const float4 attv = *(const float4*)(att + sub * 4);
  const int gw = (blockIdx.x * 256 + threadIdx.x) >> 6;
  const int nw = gridDim.x * 4;
  for (int p = gw; p < ET / 2; p += nw) {
    int e = p * 2 + half;
    int s, d; const float* ap;
    if (e < NE) { s = ei[e]; d = ei[NE + e]; ap = ea + (size_t)e * 8; }
    else { s = e - NE; d = s; ap = mattr + (size_t)(e - NE) * 8; }
    float4 a0 = *(const float4*)ap;
    float4 a1 = *(const float4*)(ap + 4);
    float4 xlv = *(const float4*)(xl + (size_t)s * 128 + sub * 4);
    float4 xrv = *(const float4*)(xr + (size_t)d * 128 + sub * 4);
    const float* xle = (const float*)&xlv;
    const float* xre = (const float*)&xrv;
    const float* ate = (const float*)&attv;
    float psum = 0.f;
#pragma unroll
    for (int c = 0; c < 4; ++c) {
      float em = a0.x * w0[c].x + a0.y * w0[c].y + a0.z * w0[c].z + a0.w * w0[c].w
               + a1.x * w1[c].x + a1.y * w1[c].y + a1.z * w1[c].z + a1.w * w1[c].w;
      float v = xle[c] + xre[c] + em;
      v = v > 0.f ? v : 0.2f * v;
      psum += v * ate[c];
    }
    psum += __shfl_xor(psum, 1);
    psum += __shfl_xor(psum, 2);
    psum += __shfl_xor(psum, 4);
    if ((sub & 7) == 0) scr[(size_t)e * 4 + (sub >> 3)] = psum;
  }
}

// per-node: softmax max/den + weighted aggregation, wave per node
__global__ __launch_bounds__(256) void k_nodered(const float* __restrict__ scr, const int2* __restrict__ csr,
                                                 const int* __restrict__ cs, const float* __restrict__ xl,
                                                 const float* __restrict__ bias,
                                                 float* __restrict__ m_out, float* __restrict__ den_out,
                                                 float* __restrict__ nout) {
  int d = (blockIdx.x * 256 + threadIdx.x) >> 6;
  int lane = threadIdx.x & 63;
  int h0 = lane >> 5;  // 0/1; second head is h0+2
  int beg = cs[d], end = cs[d + 1];
  float mx0 = -3.4e38f, mx1 = -3.4e38f;
  for (int i = beg; i < end; ++i) {
    int e = csr[i].x;
    mx0 = fmaxf(mx0, scr[(size_t)e * 4 + h0]);
    mx1 = fmaxf(mx1, scr[(size_t)e * 4 + h0 + 2]);
  }
  float acc0 = 0.f, acc1 = 0.f, dn0 = 0.f, dn1 = 0.f;
  for (int i = beg; i < end; ++i) {
    int2 es = csr[i];
    float ex0 = __expf(scr[(size_t)es.x * 4 + h0] - mx0);
    float ex1 = __expf(scr[(size_t)es.x * 4 + h0 + 2] - mx1);
    dn0 += ex0; dn1 += ex1;
    const float* xp = xl + (size_t)es.y * 128;
    acc0 += ex0 * xp[lane];
    acc1 += ex1 * xp[64 + lane];
  }
  if (lane == 0 || lane == 32) {
    m_out[d * 4 + h0] = mx0;     m_out[d * 4 + h0 + 2] = mx1;
    den_out[d * 4 + h0] = dn0;   den_out[d * 4 + h0 + 2] = dn1;
  }
  nout[(size_t)d * 128 + lane] = fmaxf(acc0 / dn0 + bias[lane], 0.f);
  nout[(size_t)d * 128 + 64 + lane] = fmaxf(acc1 / dn1 + bias[64 + lane], 0.f);
}

__global__ __launch_bounds__(256) void k_alpha(const float* __restrict__ scr, const int* __restrict__ ei,
                                               const float* __restrict__ m, const float* __restrict__ den,
                                               float* __restrict__ aout) {
  int t = blockIdx.x * 256 + threadIdx.x;
  if (t >= ET * 4) return;
  int e = t >> 2, h = t & 3;
  int d = (e < NE) ? ei[NE + e] : (e - NE);
  aout[t] = __expf(scr[t] - m[d * 4 + h]) / den[d * 4 + h];
}

// ---------------- evo L1 factorization ----------------
__global__ __launch_bounds__(256) void k_qtab(const float* __restrict__ n1, const float* __restrict__ n2,
                                              const float* __restrict__ W1T,
                                              float* __restrict__ Qo, float* __restrict__ Qd) {
  __shared__ float s1[2048], s2[2048];
  int nb = blockIdx.x * 16;
  for (int i = threadIdx.x; i < 2048; i += 256) {
    s1[i] = n1[(size_t)nb * 128 + i];
    s2[i] = n2[(size_t)nb * 128 + i];
  }
  __syncthreads();
  int m = threadIdx.x;
  float qo[16], qd[16];
#pragma unroll
  for (int i = 0; i < 16; ++i) { qo[i] = 0.f; qd[i] = 0.f; }
#pragma unroll 2
  for (int k = 0; k < 128; ++k) {
    float w0 = W1T[(size_t)k * 256 + m];
    float w1 = W1T[(size_t)(128 + k) * 256 + m];
    float w2 = W1T[(size_t)(256 + k) * 256 + m];
    float w3 = W1T[(size_t)(384 + k) * 256 + m];
#pragma unroll
    for (int i = 0; i < 16; ++i) {
      float a = s1[i * 128 + k], b = s2[i * 128 + k];
      qo[i] += a * w0 + b * w2;
      qd[i] += a * w1 + b * w3;
    }
  }
#pragma unroll
  for (int i = 0; i < 16; ++i) {
    Qo[(size_t)(nb + i) * 256 + m] = qo[i];
    Qd[(size_t)(nb + i) * 256 + m] = qd[i];
  }
}

__global__ __launch_bounds__(256) void k_distb(const int* __restrict__ od, const float* __restrict__ dm,
                                               float* __restrict__ distb) {
  int t = blockIdx.x * 256 + threadIdx.x;
  int o = od[t * 2], d = od[t * 2 + 1];
  distb[t] = dm[(size_t)o * NN + d];
}

__global__ __launch_bounds__(256) void k_evo1(const float* __restrict__ Qo, const float* __restrict__ Qd,
                                              const int* __restrict__ od, const float* __restrict__ distb,
                                              const float* __restrict__ w512, u16* __restrict__ h1) {
  __shared__ float sw[256];
  sw[threadIdx.x] = w512[threadIdx.x];
  __syncthreads();
  int t = blockIdx.x * 256 + threadIdx.x;
  int b = t >> 6, mq = (t & 63) << 2;
  int o = od[b * 2], d = od[b * 2 + 1];
  float dist = distb[b];
  const float4 qa = *(const float4*)(Qo + (size_t)o * 256 + mq);
  const float4 qc = *(const float4*)(Qd + (size_t)d * 256 + mq);
  float v0 = qa.x + qc.x + dist * sw[mq + 0];
  float v1 = qa.y + qc.y + dist * sw[mq + 1];
  float v2 = qa.z + qc.z + dist * sw[mq + 2];
  float v3 = qa.w + qc.w + dist * sw[mq + 3];
  ushort4 r;
  r.x = f2b(lrelu(v0, 0.01f)); r.y = f2b(lrelu(v1, 0.01f));
  r.z = f2b(lrelu(v2, 0.01f)); r.w = f2b(lrelu(v3, 0.01f));
  *(ushort4*)(h1 + (size_t)b * 256 + mq) = r;
}

__global__ __launch_bounds__(256) void k_catx(const int* __restrict__ od, const float* __restrict__ nv,
                                              const float* __restrict__ distb, u16* __restrict__ cat) {
  int b = blockIdx.x * 256 + threadIdx.x;
  int o = od[b * 2], d = od[b * 2 + 1];
  u16* c = cat + (size_t)b * 96 + 64;
  c[0] = f2b(nv[o * 2]);
  c[1] = f2b(nv[d * 2]);
  c[2] = f2b(nv[o * 2 + 1]);
  c[3] = f2b(nv[d * 2 + 1]);
  c[4] = f2b(distb[b]);
#pragma unroll
  for (int k = 5; k < 32; ++k) c[k] = 0;
}

// ---------------- MFMA GEMM: C = A(B x K) @ W(M x K)^T ----------------
// EPI: 0 = leaky->bf16, 1 = raw bf16 + column stats (sum,sumsq), 2 = f32 + bf16 raw
template <int NF, int EPI, int COLS>
__global__ __launch_bounds__(256) void gemm_bf16(const u16* __restrict__ A, const u16* __restrict__ W,
                                                 int K, int M,
                                                 u16* __restrict__ obf, int ld_bf,
                                                 float* __restrict__ of32, int ld_f32,
                                                 float* __restrict__ stats, float slope) {
  constexpr int CW = NF * 16;   // cols per wave
  constexpr int BN = CW * 2;    // block cols
  __shared__ u16 Alds[128 * 32];
  __shared__ u16 Blds[BN * 32];
  const int lane = threadIdx.x & 63;
  const int w = threadIdx.x >> 6;
  const int wr = w >> 1, wc = w & 1;
  int bx, by;
  if (COLS == 2) {
    const int id = blockIdx.x;
    const int g = id >> 4, t = id & 15;
    by = t >> 3;
    bx = (g << 3) + (t & 7);
  } else {
    bx = blockIdx.x; by = 0;
  }
  const size_t rowBase = (size_t)bx * 128;
  const int colBase = by * BN;

  f32x4 acc[4][NF];
  const f32x4 z4 = {0.f, 0.f, 0.f, 0.f};
#pragma unroll
  for (int m = 0; m < 4; ++m)
#pragma unroll
    for (int n = 0; n < NF; ++n) acc[m][n] = z4;

  const int sr = (w << 4) + (lane >> 2);
  const int sc = (lane & 3) << 3;
  const int KT = K >> 5;
  for (int kt = 0; kt < KT; ++kt) {
    const int kb = kt << 5;
#pragma unroll
    for (int i = 0; i < 2; ++i) {
      const u16* src = A + (rowBase + (i << 6) + sr) * (size_t)K + kb + sc;
      g2lds16(src, &Alds[((i << 6) + (w << 4)) << 5]);
    }
#pragma unroll
    for (int i = 0; i < NF / 2; ++i) {
      const u16* src = W + (size_t)(colBase + (i << 6) + sr) * K + kb + sc;
      g2lds16(src, &Blds[((i << 6) + (w << 4)) << 5]);
    }
    __syncthreads();
    const int lr = lane & 15, lk = (lane >> 4) << 3;
    bf16x8 af[4], bfr[NF];
#pragma unroll
    for (int m = 0; m < 4; ++m)
      af[m] = *(const bf16x8*)&Alds[(((wr << 6) + (m << 4) + lr) << 5) + lk];
#pragma unroll
    for (int n = 0; n < NF; ++n)
      bfr[n] = *(const bf16x8*)&Blds[((wc * CW + (n << 4) + lr) << 5) + lk];
#pragma unroll
    for (int m = 0; m < 4; ++m)
#pragma unroll
      for (int n = 0; n < NF; ++n)
        acc[m][n] = __builtin_amdgcn_mfma_f32_16x16x32_bf16(af[m], bfr[n], acc[m][n], 0, 0, 0);
    __syncthreads();
  }

  const int lr = lane & 15, lg = lane >> 4;
  float cs[NF], cq[NF];
#pragma unroll
  for (int n = 0; n < NF; ++n) { cs[n] = 0.f; cq[n] = 0.f; }
#pragma unroll
  for (int m = 0; m < 4; ++m) {
#pragma unroll
    for (int n = 0; n < NF; ++n) {
      const int col = colBase + wc * CW + (n << 4) + lr;
#pragma unroll
      for (int j = 0; j < 4; ++j) {
        const size_t row = rowBase + (wr << 6) + (m << 4) + (lg << 2) + j;
        float v = acc[m][n][j];
        if (EPI == 0) {
          v = v > 0.f ? v : v * slope;
          obf[row * ld_bf + col] = f2b(v);
        } else if (EPI == 1) {
          obf[row * ld_bf + col] = f2b(v);
          cs[n] += v; cq[n] += v * v;
        } else {
          of32[row * ld_f32 + col] = v;
          obf[row * ld_bf + col] = f2b(v);
        }
      }
    }
  }
  if (EPI == 1) {
#pragma unroll
    for (int n = 0; n < NF; ++n) {
      float s = cs[n], q = cq[n];
      s += __shfl_xor(s, 16); s += __shfl_xor(s, 32);
      q += __shfl_xor(q, 16); q += __shfl_xor(q, 32);
      if (lane < 16) {
        const int col = colBase + wc * CW + (n << 4) + lane;
        atomicAdd(&stats[col], s);
        atomicAdd(&stats[M + col], q);
      }
    }
  }
}

// ---------------- BN + leaky (16B/lane) ----------------
__global__ __launch_bounds__(256) void k_bnact(const u16* __restrict__ pre, u16* __restrict__ act,
                                               const float* __restrict__ st, const float* __restrict__ g,
                                               const float* __restrict__ b, int M, float invB) {
  size_t idx = ((size_t)blockIdx.x * 256 + threadIdx.x) << 3;
  int c0 = (int)(idx & (size_t)(M - 1));
  bf16x8 u = *(const bf16x8*)(pre + idx);
  u16 rr[8];
#pragma unroll
  for (int j = 0; j < 8; ++j) {
    int c = c0 + j;
    float mu = st[c] * invB;
    float var = st[M + c] * invB - mu * mu;
    float v = (b2f((u16)u[j]) - mu) * rsqrtf(var + 1e-5f) * g[c] + b[c];
    rr[j] = f2b(lrelu(v, 0.01f));
  }
  bf16x8 r;
#pragma unroll
  for (int j = 0; j < 8; ++j) r[j] = (short)rr[j];
  *(bf16x8*)(act + idx) = r;
}

__global__ __launch_bounds__(256) void k_fout(const u16* __restrict__ h, const float* __restrict__ W,
                                              float* __restrict__ out) {
  __shared__ float sw[128];
  if (threadIdx.x < 128) sw[threadIdx.x] = W[threadIdx.x];
  __syncthreads();
  int b = blockIdx.x * 256 + threadIdx.x;
  const u16* hp = h + (size_t)b * 128;
  float acc = 0.f;
#pragma unroll
  for (int k = 0; k < 128; k += 4) {
    ushort4 u = *(const ushort4*)(hp + k);
    acc += b2f(u.x) * sw[k] + b2f(u.y) * sw[k + 1] + b2f(u.z) * sw[k + 2] + b2f(u.w) * sw[k + 3];
  }
  out[b] = acc;
}

// ---------------- launch ----------------
extern "C" void kernel_launch(void* const* d_in, const int* in_sizes, int n_in,
                              void* d_out, int out_size, void* d_ws, size_t ws_size,
                              hipStream_t stream) {
  (void)in_sizes; (void)n_in; (void)out_size; (void)ws_size;

  const float* x[2] = {(const float*)d_in[0], (const float*)d_in[3]};
  const int* ei[2] = {(const int*)d_in[1], (const int*)d_in[4]};
  const float* ea[2] = {(const float*)d_in[2], (const float*)d_in[5]};
  const float* dm = (const float*)d_in[6];
  const float* nv = (const float*)d_in[7];
  const int* od = (const int*)d_in[8];
  const float* Wl[2] = {(const float*)d_in[9], (const float*)d_in[16]};
  const float* bl[2] = {(const float*)d_in[10], (const float*)d_in[17]};
  const float* Wr[2] = {(const float*)d_in[11], (const float*)d_in[18]};
  const float* br[2] = {(const float*)d_in[12], (const float*)d_in[19]};
  const float* We[2] = {(const float*)d_in[13], (const float*)d_in[20]};
  const float* att[2] = {(const float*)d_in[14], (const float*)d_in[21]};
  const float* bia[2] = {(const float*)d_in[15], (const float*)d_in[22]};
  const float* eW1 = (const float*)d_in[23];
  const float* eW2 = (const float*)d_in[24];
  const float* eW3 = (const float*)d_in[25];
  const float* eW4 = (const float*)d_in[26];
  const float* eWo = (const float*)d_in[27];
  const float* fW1 = (const float*)d_in[28];
  const float* fW2 = (const float*)d_in[29];
  const float* fW3 = (const float*)d_in[30];
  const float* fW4 = (const float*)d_in[31];
  const float* fWo = (const float*)d_in[32];
  const float* fg[4] = {(const float*)d_in[33], (const float*)d_in[35], (const float*)d_in[37], (const float*)d_in[39]};
  const float* fb[4] = {(const float*)d_in[34], (const float*)d_in[36], (const float*)d_in[38], (const float*)d_in[40]};

  float* out_inf = (float*)d_out;
  float* out_a1 = out_inf + NB;
  float* out_a2 = out_a1 + (size_t)ET * 4;
  float* out_evo = out_a2 + (size_t)ET * 4;

  // ---- workspace carve ----
  char* base = (char*)d_ws;
  size_t cur = 0;
  auto carve = [&](size_t bytes) -> char* {
    char* p = base + cur;
    cur += (bytes + 255) & ~(size_t)255;
    return p;
  };
  u16* bufA = (u16*)carve((size_t)NB * 256 * 2);
  u16* bufB = (u16*)carve((size_t)NB * 256 * 2);
  const size_t clusterOff = cur;  // cat (B x 96 bf16) aliases everything below (dead by then)
  float* n1 = (float*)carve((size_t)NN * 128 * 4);
  float* n2 = (float*)carve((size_t)NN * 128 * 4);
  float* Qo = (float*)carve((size_t)NN * 256 * 4);
  float* Qd = (float*)carve((size_t)NN * 256 * 4);
  float* xl = (float*)carve((size_t)NN * 128 * 4);
  float* xr = (float*)carve((size_t)NN * 128 * 4);
  int* cnt = (int*)carve((size_t)(NN + 1) * 4);
  int* wr = (int*)carve((size_t)NN * 4);
  int* cs = (int*)carve((size_t)(NN + 1) * 4);
  int2* csr = (int2*)carve((size_t)ET * 8);
  float* m_out = (float*)carve((size_t)NN * 4 * 4);
  float* den_out = (float*)carve((size_t)NN * 4 * 4);
  float* asum = (float*)carve((size_t)NN * 8 * 4);
  float* scr = (float*)carve((size_t)ET * 4 * 4);
  // ensure the alias cluster is big enough for cat
  const size_t catBytes = (size_t)NB * 96 * 2;
  if (cur < clusterOff + catBytes) cur = (clusterOff + catBytes + 255) & ~(size_t)255;
  u16* cat = (u16*)(base + clusterOff);
  // --- below here is NOT aliased by cat ---
  float* distb = (float*)carve((size_t)NB * 4);
  float* w512 = (float*)carve(1024);
  float* W1T = (float*)carve(512 * 256 * 4);
  float* stats = (float*)carve(1792 * 4);
  float* st[4] = {stats, stats + 512, stats + 1024, stats + 1536};
  u16* eW2b = (u16*)carve(256 * 256 * 2);
  u16* eW3b = (u16*)carve(256 * 256 * 2);
  u16* eW4b = (u16*)carve(128 * 256 * 2);
  u16* eWob = (u16*)carve(64 * 128 * 2);
  u16* fW1b = (u16*)carve(256 * 96 * 2);
  u16* fW2b = (u16*)carve(256 * 256 * 2);
  u16* fW3b = (u16*)carve(256 * 256 * 2);
  u16* fW4b = (u16*)carve(128 * 256 * 2);

  // ---- weight prep ----
  k_convw<<<256, 256, 0, stream>>>(eW2, eW2b, 256, 256, 256);
  k_convw<<<256, 256, 0, stream>>>(eW3, eW3b, 256, 256, 256);
  k_convw<<<128, 256, 0, stream>>>(eW4, eW4b, 128, 256, 256);
  k_convw<<<32, 256, 0, stream>>>(eWo, eWob, 64, 128, 128);
  k_convw<<<96, 256, 0, stream>>>(fW1, fW1b, 256, 69, 96);
  k_convw<<<256, 256, 0, stream>>>(fW2, fW2b, 256, 256, 256);
  k_convw<<<256, 256, 0, stream>>>(fW3, fW3b, 256, 256, 256);
  k_convw<<<128, 256, 0, stream>>>(fW4, fW4b, 128, 256, 256);
  k_w512<<<1, 256, 0, stream>>>(eW1, w512);
  k_trw1<<<256, 256, 0, stream>>>(eW1, W1T);
  hipMemsetAsync(stats, 0, 1792 * 4, stream);
  k_distb<<<NB / 256, 256, 0, stream>>>(od, dm, distb);

  // ---- GATv2 x2 (CSR-based, no heavy atomics) ----
  float* nout[2] = {n1, n2};
  float* aout[2] = {out_a1, out_a2};
  const int EB = (ET + 255) / 256;
  for (int gi = 0; gi < 2; ++gi) {
    hipMemsetAsync(cnt, 0, (size_t)(NN + 1) * 4, stream);
    hipMemsetAsync(wr, 0, (size_t)NN * 4, stream);
    k_count<<<EB, 256, 0, stream>>>(ei[gi], cnt);
    k_scan<<<1, 1024, 0, stream>>>(cnt, cs);
    k_fill<<<EB, 256, 0, stream>>>(ei[gi], cs, wr, csr);
    k_asum<<<NN / 4, 256, 0, stream>>>(csr, cs, ea[gi], asum);
    k_xlr<<<NN / 2, 256, 0, stream>>>(x[gi], Wl[gi], bl[gi], Wr[gi], br[gi], xl, xr);
    k_scr<<<2048, 256, 0, stream>>>(xl, xr, ei[gi], ea[gi], asum, We[gi], att[gi], scr);
    k_nodered<<<NN / 4, 256, 0, stream>>>(scr, csr, cs, xl, bia[gi], m_out, den_out, nout[gi]);
    k_alpha<<<(ET * 4 + 255) / 256, 256, 0, stream>>>(scr, ei[gi], m_out, den_out, aout[gi]);
  }

  // ---- evo ----
  k_qtab<<<NN / 16, 256, 0, stream>>>(n1, n2, W1T, Qo, Qd);
  k_evo1<<<NB * 64 / 256, 256, 0, stream>>>(Qo, Qd, od, distb, w512, bufA);
  k_catx<<<NB / 256, 256, 0, stream>>>(od, nv, distb, cat);  // after evo1 (cat aliases GAT scratch)

  const float invB = 1.0f / (float)NB;
  const int G2 = NB / 128 * 2, G1 = NB / 128;
  gemm_bf16<4, 0, 2><<<G2, 256, 0, stream>>>(bufA, eW2b, 256, 256, bufB, 256, nullptr, 0, nullptr, 0.01f);
  gemm_bf16<4, 0, 2><<<G2, 256, 0, stream>>>(bufB, eW3b, 256, 256, bufA, 256, nullptr, 0, nullptr, 0.01f);
  gemm_bf16<4, 0, 1><<<G1, 256, 0, stream>>>(bufA, eW4b, 256, 128, bufB, 128, nullptr, 0, nullptr, 0.01f);
  gemm_bf16<2, 2, 1><<<G1, 256, 0, stream>>>(bufB, eWob, 128, 64, cat, 96, out_evo, 64, nullptr, 0.f);

  // ---- flow ----
  gemm_bf16<4, 1, 2><<<G2, 256, 0, stream>>>(cat, fW1b, 96, 256, bufA, 256, nullptr, 0, st[0], 0.f);
  k_bnact<<<NB * 256 / 8 / 256, 256, 0, stream>>>(bufA, bufB, st[0], fg[0], fb[0], 256, invB);
  gemm_bf16<4, 1, 2><<<G2, 256, 0, stream>>>(bufB, fW2b, 256, 256, bufA, 256, nullptr, 0, st[1], 0.f);
  k_bnact<<<NB * 256 / 8 / 256, 256, 0, stream>>>(bufA, bufB, st[1], fg[1], fb[1], 256, invB);
  gemm_bf16<4, 1, 2><<<G2, 256, 0, stream>>>(bufB, fW3b, 256, 256, bufA, 256, nullptr, 0, st[2], 0.f);
  k_bnact<<<NB * 256 / 8 / 256, 256, 0, stream>>>(bufA, bufB, st[2], fg[2], fb[2], 256, invB);
  gemm_bf16<4, 1, 1><<<G1, 256, 0, stream>>>(bufB, fW4b, 256, 128, bufA, 128, nullptr, 0, st[3], 0.f);
  k_bnact<<<NB * 128 / 8 / 256, 256, 0, stream>>>(bufA, bufB, st[3], fg[3], fb[3], 128, invB);
  k_fout<<<NB / 256, 256, 0, stream>>>(bufB, fWo, out_inf);
}

// Round 4
// 1617.332 us; speedup vs baseline: 1.7522x; 1.0321x over previous
//
#include <hip/hip_runtime.h>

typedef unsigned short u16;
typedef unsigned int u32;

#define NN 10000      // nodes
#define NE 320000     // edges
#define ET 330000     // edges + self loops
#define NB 262144     // batch

typedef __attribute__((ext_vector_type(8))) short bf16x8;
typedef __attribute__((ext_vector_type(4))) float f32x4;

__device__ __forceinline__ u16 f2b(float f) {
  u32 u = __float_as_uint(f);
  u += 0x7fffu + ((u >> 16) & 1u);
  return (u16)(u >> 16);
}
__device__ __forceinline__ float b2f(u16 h) {
  return __uint_as_float(((u32)h) << 16);
}
__device__ __forceinline__ float lrelu(float v, float s) { return v > 0.f ? v : v * s; }

__device__ __forceinline__ void g2lds16(const void* g, void* l) {
  __builtin_amdgcn_global_load_lds((const __attribute__((address_space(1))) void*)g,
                                   (__attribute__((address_space(3))) void*)l, 16, 0, 0);
}

// ---------------- merged prep: weight bf16 conversion + W1T + w512 + comb ----------------
// block ranges: [0,256) eW2b | [256,512) eW3b | [512,640) eW4b | [640,672) eWob
//               [672,928) fW2b | [928,1184) fW3b | [1184,1312) fW4b
//               [1312,1568) W1T | 1568 w512 | [1569,1825) combW
__global__ __launch_bounds__(256) void k_prep(const float* __restrict__ eW2, const float* __restrict__ eW3,
                                              const float* __restrict__ eW4, const float* __restrict__ eWo,
                                              const float* __restrict__ fW1, const float* __restrict__ fW2,
                                              const float* __restrict__ fW3, const float* __restrict__ fW4,
                                              const float* __restrict__ eW1,
                                              u16* eW2b, u16* eW3b, u16* eW4b, u16* eWob,
                                              u16* fW2b, u16* fW3b, u16* fW4b,
                                              float* W1T, float* w512, u16* combW) {
  const int blk = blockIdx.x, tid = threadIdx.x;
  if (blk < 256) {
    int t = blk * 256 + tid; eW2b[t] = f2b(eW2[t]);
  } else if (blk < 512) {
    int t = (blk - 256) * 256 + tid; eW3b[t] = f2b(eW3[t]);
  } else if (blk < 640) {
    int t = (blk - 512) * 256 + tid; eW4b[t] = f2b(eW4[t]);
  } else if (blk < 672) {
    int t = (blk - 640) * 256 + tid; eWob[t] = f2b(eWo[t]);
  } else if (blk < 928) {
    int t = (blk - 672) * 256 + tid; fW2b[t] = f2b(fW2[t]);
  } else if (blk < 1184) {
    int t = (blk - 928) * 256 + tid; fW3b[t] = f2b(fW3[t]);
  } else if (blk < 1312) {
    int t = (blk - 1184) * 256 + tid; fW4b[t] = f2b(fW4[t]);
  } else if (blk < 1568) {
    int m = blk - 1312;
    for (int k = tid; k < 512; k += 256) W1T[(size_t)k * 256 + m] = eW1[(size_t)m * 513 + k];
  } else if (blk == 1568) {
    w512[tid] = eW1[(size_t)tid * 513 + 512];
  } else {
    int m = blk - 1569;
    int k = tid;
    if (k < 160) {
      float v = 0.f;
      if (k < 128) {
        const float* fr = fW1 + (size_t)m * 69;
        for (int j = 0; j < 64; ++j) v += fr[j] * eWo[(size_t)j * 128 + k];
      } else if (k < 133) {
        v = fW1[(size_t)m * 69 + 64 + (k - 128)];
      }
      combW[(size_t)m * 160 + k] = f2b(v);
    }
  }
}

// distb + S columns (128..159) of bufC
__global__ __launch_bounds__(256) void k_sprep(const int* __restrict__ od, const float* __restrict__ dm,
                                               const float* __restrict__ nv,
                                               float* __restrict__ distb, u16* __restrict__ bufC) {
  int b = blockIdx.x * 256 + threadIdx.x;
  int o = od[b * 2], d = od[b * 2 + 1];
  float dist = dm[(size_t)o * NN + d];
  distb[b] = dist;
  u16 tmp[32];
  tmp[0] = f2b(nv[o * 2]);
  tmp[1] = f2b(nv[d * 2]);
  tmp[2] = f2b(nv[o * 2 + 1]);
  tmp[3] = f2b(nv[d * 2 + 1]);
  tmp[4] = f2b(dist);
#pragma unroll
  for (int k = 5; k < 32; ++k) tmp[k] = 0;
  u16* p = bufC + (size_t)b * 160 + 128;
#pragma unroll
  for (int k = 0; k < 4; ++k) *(bf16x8*)(p + k * 8) = *(bf16x8*)(tmp + k * 8);
}

// ---------------- CSR build (per graph) ----------------
__global__ __launch_bounds__(256) void k_count(const int* __restrict__ ei, int* __restrict__ cnt) {
  int t = blockIdx.x * 256 + threadIdx.x;
  if (t >= ET) return;
  int d = (t < NE) ? ei[NE + t] : (t - NE);
  atomicAdd(&cnt[d], 1);
}

__global__ __launch_bounds__(1024) void k_scan(const int* __restrict__ cnt, int* __restrict__ cs) {
  __shared__ int part[1024];
  int tid = threadIdx.x;
  int base = tid * 10;
  int local[10];
  int s = 0;
#pragma unroll
  for (int i = 0; i < 10; ++i) {
    int idx = base + i;
    int v = (idx < NN) ? cnt[idx] : 0;
    local[i] = s; s += v;
  }
  part[tid] = s;
  __syncthreads();
  for (int off = 1; off < 1024; off <<= 1) {
    int v = (tid >= off) ? part[tid - off] : 0;
    __syncthreads();
    part[tid] += v;
    __syncthreads();
  }
  int pre = (tid > 0) ? part[tid - 1] : 0;
#pragma unroll
  for (int i = 0; i < 10; ++i) {
    int idx = base + i;
    if (idx < NN) cs[idx] = pre + local[i];
  }
  if (tid == 1023) cs[NN] = part[1023];
}

__global__ __launch_bounds__(256) void k_fill(const int* __restrict__ ei, const int* __restrict__ cs,
                                              int* __restrict__ wr, int2* __restrict__ csr) {
  int t = blockIdx.x * 256 + threadIdx.x;
  if (t >= ET) return;
  int s, d;
  if (t < NE) { s = ei[t]; d = ei[NE + t]; } else { s = t - NE; d = s; }
  int pos = atomicAdd(&wr[d], 1);
  csr[cs[d] + pos] = make_int2(t, s);
}

__global__ __launch_bounds__(256) void k_asum(const int2* __restrict__ csr, const int* __restrict__ cs,
                                              const float* __restrict__ ea, float* __restrict__ asum) {
  int wid = (blockIdx.x * 256 + threadIdx.x) >> 6;
  int lane = threadIdx.x & 63;
  int beg = cs[wid], end = cs[wid + 1];
  int j = lane & 7, slot = lane >> 3;
  float acc = 0.f;
  for (int i = beg + slot; i < end; i += 8) {
    int e = csr[i].x;
    if (e < NE) acc += ea[(size_t)e * 8 + j];
  }
  acc += __shfl_xor(acc, 8);
  acc += __shfl_xor(acc, 16);
  acc += __shfl_xor(acc, 32);
  if (lane < 8) {
    float dr = (float)(end - beg - 1);
    asum[(size_t)wid * 8 + lane] = acc / fmaxf(dr, 1.f);
  }
}

// ---------------- GAT ----------------
__global__ __launch_bounds__(256) void k_xlr(const float* __restrict__ x,
                                             const float* __restrict__ Wl, const float* __restrict__ bl,
                                             const float* __restrict__ Wr, const float* __restrict__ br,
                                             float* __restrict__ xl, float* __restrict__ xr) {
  __shared__ float sx[128];
  int nb = blockIdx.x * 2;
  for (int i = threadIdx.x; i < 128; i += 256) sx[i] = x[(size_t)nb * 64 + i];
  __syncthreads();
  int half = threadIdx.x >> 7;
  int node = nb + half;
  int m = threadIdx.x & 127;
  const float* xv = sx + (half << 6);
  float al = bl[m], ar = br[m];
  const float* wl = Wl + (size_t)m * 64;
  const float* wr = Wr + (size_t)m * 64;
#pragma unroll 8
  for (int k = 0; k < 64; ++k) { float xk = xv[k]; al += xk * wl[k]; ar += xk * wr[k]; }
  xl[(size_t)node * 128 + m] = al;
  xr[(size_t)node * 128 + m] = ar;
}

__global__ __launch_bounds__(256) void k_scr(const float* __restrict__ xl, const float* __restrict__ xr,
                                             const int* __restrict__ ei, const float* __restrict__ ea,
                                             const float* __restrict__ mattr,
                                             const float* __restrict__ We, const float* __restrict__ att,
                                             float* __restrict__ scr) {
  const int lane = threadIdx.x & 63;
  const int sub = lane & 31;
  const int half = lane >> 5;
  float4 w0[4], w1[4];
#pragma unroll
  for (int c = 0; c < 4; ++c) {
    const float* wp = We + (size_t)(sub * 4 + c) * 8;
    w0[c] = *(const float4*)wp;
    w1[c] = *(const float4*)(wp + 4);
  }
  const float4 attv = *(const float4*)(att + sub * 4);
  const int gw = (blockIdx.x * 256 + threadIdx.x) >> 6;
  const int nw = gridDim.x * 4;
  for (int p = gw; p < ET / 2; p += nw) {
    int e = p * 2 + half;
    int s, d; const float* ap;
    if (e < NE) { s = ei[e]; d = ei[NE + e]; ap = ea + (size_t)e * 8; }
    else { s = e - NE; d = s; ap = mattr + (size_t)(e - NE) * 8; }
    float4 a0 = *(const float4*)ap;
    float4 a1 = *(const float4*)(ap + 4);
    float4 xlv = *(const float4*)(xl + (size_t)s * 128 + sub * 4);
    float4 xrv = *(const float4*)(xr + (size_t)d * 128 + sub * 4);
    const float* xle = (const float*)&xlv;
    const float* xre = (const float*)&xrv;
    const float* ate = (const float*)&attv;
    float psum = 0.f;
#pragma unroll
    for (int c = 0; c < 4; ++c) {
      float em = a0.x * w0[c].x + a0.y * w0[c].y + a0.z * w0[c].z + a0.w * w0[c].w
               + a1.x * w1[c].x + a1.y * w1[c].y + a1.z * w1[c].z + a1.w * w1[c].w;
      float v = xle[c] + xre[c] + em;
      v = v > 0.f ? v : 0.2f * v;
      psum += v * ate[c];
    }
    psum += __shfl_xor(psum, 1);
    psum += __shfl_xor(psum, 2);
    psum += __shfl_xor(psum, 4);
    if ((sub & 7) == 0) scr[(size_t)e * 4 + (sub >> 3)] = psum;
  }
}

__global__ __launch_bounds__(256) void k_nodered(const float* __restrict__ scr, const int2* __restrict__ csr,
                                                 const int* __restrict__ cs, const float* __restrict__ xl,
                                                 const float* __restrict__ bias,
                                                 float* __restrict__ m_out, float* __restrict__ den_out,
                                                 float* __restrict__ nout) {
  int d = (blockIdx.x * 256 + threadIdx.x) >> 6;
  int lane = threadIdx.x & 63;
  int h0 = lane >> 5;
  int beg = cs[d], end = cs[d + 1];
  float mx0 = -3.4e38f, mx1 = -3.4e38f;
  for (int i = beg; i < end; ++i) {
    int e = csr[i].x;
    mx0 = fmaxf(mx0, scr[(size_t)e * 4 + h0]);
    mx1 = fmaxf(mx1, scr[(size_t)e * 4 + h0 + 2]);
  }
  float acc0 = 0.f, acc1 = 0.f, dn0 = 0.f, dn1 = 0.f;
  for (int i = beg; i < end; ++i) {
    int2 es = csr[i];
    float ex0 = __expf(scr[(size_t)es.x * 4 + h0] - mx0);
    float ex1 = __expf(scr[(size_t)es.x * 4 + h0 + 2] - mx1);
    dn0 += ex0; dn1 += ex1;
    const float* xp = xl + (size_t)es.y * 128;
    acc0 += ex0 * xp[lane];
    acc1 += ex1 * xp[64 + lane];
  }
  if (lane == 0 || lane == 32) {
    m_out[d * 4 + h0] = mx0;     m_out[d * 4 + h0 + 2] = mx1;
    den_out[d * 4 + h0] = dn0;   den_out[d * 4 + h0 + 2] = dn1;
  }
  nout[(size_t)d * 128 + lane] = fmaxf(acc0 / dn0 + bias[lane], 0.f);
  nout[(size_t)d * 128 + 64 + lane] = fmaxf(acc1 / dn1 + bias[64 + lane], 0.f);
}

__global__ __launch_bounds__(256) void k_alpha(const float* __restrict__ scr, const int* __restrict__ ei,
                                               const float* __restrict__ m, const float* __restrict__ den,
                                               float* __restrict__ aout) {
  int t = blockIdx.x * 256 + threadIdx.x;
  if (t >= ET * 4) return;
  int e = t >> 2, h = t & 3;
  int d = (e < NE) ? ei[NE + e] : (e - NE);
  aout[t] = __expf(scr[t] - m[d * 4 + h]) / den[d * 4 + h];
}

// ---------------- evo L1 factorization ----------------
__global__ __launch_bounds__(256) void k_qtab(const float* __restrict__ n1, const float* __restrict__ n2,
                                              const float* __restrict__ W1T,
                                              float* __restrict__ Qo, float* __restrict__ Qd) {
  __shared__ float s1[2048], s2[2048];
  int nb = blockIdx.x * 16;
  for (int i = threadIdx.x; i < 2048; i += 256) {
    s1[i] = n1[(size_t)nb * 128 + i];
    s2[i] = n2[(size_t)nb * 128 + i];
  }
  __syncthreads();
  int m = threadIdx.x;
  float qo[16], qd[16];
#pragma unroll
  for (int i = 0; i < 16; ++i) { qo[i] = 0.f; qd[i] = 0.f; }
#pragma unroll 2
  for (int k = 0; k < 128; ++k) {
    float w0 = W1T[(size_t)k * 256 + m];
    float w1 = W1T[(size_t)(128 + k) * 256 + m];
    float w2 = W1T[(size_t)(256 + k) * 256 + m];
    float w3 = W1T[(size_t)(384 + k) * 256 + m];
#pragma unroll
    for (int i = 0; i < 16; ++i) {
      float a = s1[i * 128 + k], b = s2[i * 128 + k];
      qo[i] += a * w0 + b * w2;
      qd[i] += a * w1 + b * w3;
    }
  }
#pragma unroll
  for (int i = 0; i < 16; ++i) {
    Qo[(size_t)(nb + i) * 256 + m] = qo[i];
    Qd[(size_t)(nb + i) * 256 + m] = qd[i];
  }
}

__global__ __launch_bounds__(256) void k_evo1(const float* __restrict__ Qo, const float* __restrict__ Qd,
                                              const int* __restrict__ od, const float* __restrict__ distb,
                                              const float* __restrict__ w512, u16* __restrict__ h1) {
  __shared__ float sw[256];
  sw[threadIdx.x] = w512[threadIdx.x];
  __syncthreads();
  int t = blockIdx.x * 256 + threadIdx.x;
  int b = t >> 6, mq = (t & 63) << 2;
  int o = od[b * 2], d = od[b * 2 + 1];
  float dist = distb[b];
  const float4 qa = *(const float4*)(Qo + (size_t)o * 256 + mq);
  const float4 qc = *(const float4*)(Qd + (size_t)d * 256 + mq);
  float v0 = qa.x + qc.x + dist * sw[mq + 0];
  float v1 = qa.y + qc.y + dist * sw[mq + 1];
  float v2 = qa.z + qc.z + dist * sw[mq + 2];
  float v3 = qa.w + qc.w + dist * sw[mq + 3];
  ushort4 r;
  r.x = f2b(lrelu(v0, 0.01f)); r.y = f2b(lrelu(v1, 0.01f));
  r.z = f2b(lrelu(v2, 0.01f)); r.w = f2b(lrelu(v3, 0.01f));
  *(ushort4*)(h1 + (size_t)b * 256 + mq) = r;
}

// ---------------- MFMA GEMM with 2-phase LDS double-buffer prefetch ----------------
// C = A(B x K, row-stride lda) @ W(M x K)^T
// EPI: 0 = leaky(0.01)->bf16 | 1 = raw bf16 + column stats (sum,sumsq) | 2 = f32-only
template <int NF, int EPI, int COLS>
__global__ __launch_bounds__(256) void gemm_bf16(const u16* __restrict__ A, const u16* __restrict__ W,
                                                 int K, size_t lda, int M,
                                                 u16* __restrict__ obf, int ld_bf,
                                                 float* __restrict__ of32, float* __restrict__ stats) {
  constexpr int CW = NF * 16;
  constexpr int BN = CW * 2;
  __shared__ alignas(16) u16 Alds[2][128 * 32];
  __shared__ alignas(16) u16 Blds[2][BN * 32];
  const int lane = threadIdx.x & 63;
  const int w = threadIdx.x >> 6;
  const int wr = w >> 1, wc = w & 1;
  int bx, by;
  if (COLS == 2) {
    const int id = blockIdx.x;
    const int g = id >> 4, t = id & 15;
    by = t >> 3;
    bx = (g << 3) + (t & 7);
  } else {
    bx = blockIdx.x; by = 0;
  }
  const size_t rowBase = (size_t)bx * 128;
  const int colBase = by * BN;

  f32x4 acc[4][NF];
  const f32x4 z4 = {0.f, 0.f, 0.f, 0.f};
#pragma unroll
  for (int m = 0; m < 4; ++m)
#pragma unroll
    for (int n = 0; n < NF; ++n) acc[m][n] = z4;

  const int sr = (w << 4) + (lane >> 2);
  const int sc = (lane & 3) << 3;
  const int KT = K >> 5;

  auto stage = [&](int buf, int kb) {
#pragma unroll
    for (int i = 0; i < 2; ++i) {
      const u16* src = A + (rowBase + (i << 6) + sr) * lda + kb + sc;
      g2lds16(src, &Alds[buf][((i << 6) + (w << 4)) << 5]);
    }
#pragma unroll
    for (int i = 0; i < NF / 2; ++i) {
      const u16* src = W + (size_t)(colBase + (i << 6) + sr) * K + kb + sc;
      g2lds16(src, &Blds[buf][((i << 6) + (w << 4)) << 5]);
    }
  };

  stage(0, 0);
  int cur = 0;
  for (int kt = 0; kt < KT; ++kt) {
    if (kt + 1 < KT) {
      stage(cur ^ 1, (kt + 1) << 5);
      if constexpr (NF == 4)
        asm volatile("s_waitcnt vmcnt(4)" ::: "memory");
      else
        asm volatile("s_waitcnt vmcnt(3)" ::: "memory");
    } else {
      asm volatile("s_waitcnt vmcnt(0)" ::: "memory");
    }
    __builtin_amdgcn_sched_barrier(0);
    __builtin_amdgcn_s_barrier();
    const int lr = lane & 15, lk = (lane >> 4) << 3;
    bf16x8 af[4], bfr[NF];
#pragma unroll
    for (int m = 0; m < 4; ++m)
      af[m] = *(const bf16x8*)&Alds[cur][(((wr << 6) + (m << 4) + lr) << 5) + lk];
#pragma unroll
    for (int n = 0; n < NF; ++n)
      bfr[n] = *(const bf16x8*)&Blds[cur][((wc * CW + (n << 4) + lr) << 5) + lk];
#pragma unroll
    for (int m = 0; m < 4; ++m)
#pragma unroll
      for (int n = 0; n < NF; ++n)
        acc[m][n] = __builtin_amdgcn_mfma_f32_16x16x32_bf16(af[m], bfr[n], acc[m][n], 0, 0, 0);
    __builtin_amdgcn_sched_barrier(0);
    __builtin_amdgcn_s_barrier();
    cur ^= 1;
  }

  const int lr = lane & 15, lg = lane >> 4;
  float cs[NF], cq[NF];
#pragma unroll
  for (int n = 0; n < NF; ++n) { cs[n] = 0.f; cq[n] = 0.f; }
#pragma unroll
  for (int m = 0; m < 4; ++m) {
#pragma unroll
    for (int n = 0; n < NF; ++n) {
      const int col = colBase + wc * CW + (n << 4) + lr;
#pragma unroll
      for (int j = 0; j < 4; ++j) {
        const size_t row = rowBase + (wr << 6) + (m << 4) + (lg << 2) + j;
        float v = acc[m][n][j];
        if (EPI == 0) {
          v = v > 0.f ? v : v * 0.01f;
          obf[row * ld_bf + col] = f2b(v);
        } else if (EPI == 1) {
          obf[row * ld_bf + col] = f2b(v);
          cs[n] += v; cq[n] += v * v;
        } else {
          of32[row * M + col] = v;
        }
      }
    }
  }
  if (EPI == 1) {
#pragma unroll
    for (int n = 0; n < NF; ++n) {
      float s = cs[n], q = cq[n];
      s += __shfl_xor(s, 16); s += __shfl_xor(s, 32);
      q += __shfl_xor(q, 16); q += __shfl_xor(q, 32);
      if (lane < 16) {
        const int col = colBase + wc * CW + (n << 4) + lane;
        atomicAdd(&stats[col], s);
        atomicAdd(&stats[M + col], q);
      }
    }
  }
}

// ---------------- BN + leaky (16B/lane) ----------------
__global__ __launch_bounds__(256) void k_bnact(const u16* __restrict__ pre, u16* __restrict__ act,
                                               const float* __restrict__ st, const float* __restrict__ g,
                                               const float* __restrict__ b, int M, float invB) {
  size_t idx = ((size_t)blockIdx.x * 256 + threadIdx.x) << 3;
  int c0 = (int)(idx & (size_t)(M - 1));
  bf16x8 u = *(const bf16x8*)(pre + idx);
  u16 rr[8];
#pragma unroll
  for (int j = 0; j < 8; ++j) {
    int c = c0 + j;
    float mu = st[c] * invB;
    float var = st[M + c] * invB - mu * mu;
    float v = (b2f((u16)u[j]) - mu) * rsqrtf(var + 1e-5f) * g[c] + b[c];
    rr[j] = f2b(lrelu(v, 0.01f));
  }
  bf16x8 r;
#pragma unroll
  for (int j = 0; j < 8; ++j) r[j] = (short)rr[j];
  *(bf16x8*)(act + idx) = r;
}

// ---------------- fused BN4 + final dot ----------------
__global__ __launch_bounds__(256) void k_fout4(const u16* __restrict__ pre, const float* __restrict__ st,
                                               const float* __restrict__ g, const float* __restrict__ b,
                                               const float* __restrict__ W, float* __restrict__ out,
                                               float invB) {
  __shared__ float smu[128], srs[128], sg[128], sb[128], sw[128];
  if (threadIdx.x < 128) {
    int c = threadIdx.x;
    float mu = st[c] * invB;
    float var = st[128 + c] * invB - mu * mu;
    smu[c] = mu;
    srs[c] = rsqrtf(var + 1e-5f);
    sg[c] = g[c];
    sb[c] = b[c];
    sw[c] = W[c];
  }
  __syncthreads();
  int bi = blockIdx.x * 256 + threadIdx.x;
  const u16* hp = pre + (size_t)bi * 128;
  float acc = 0.f;
#pragma unroll
  for (int k = 0; k < 128; k += 8) {
    bf16x8 u = *(const bf16x8*)(hp + k);
#pragma unroll
    for (int j = 0; j < 8; ++j) {
      int c = k + j;
      float v = (b2f((u16)u[j]) - smu[c]) * srs[c] * sg[c] + sb[c];
      v = b2f(f2b(lrelu(v, 0.01f)));  // keep bf16 rounding -> bit-identical to bnact+fout
      acc += v * sw[c];
    }
  }
  out[bi] = acc;
}

// ---------------- launch ----------------
extern "C" void kernel_launch(void* const* d_in, const int* in_sizes, int n_in,
                              void* d_out, int out_size, void* d_ws, size_t ws_size,
                              hipStream_t stream) {
  (void)in_sizes; (void)n_in; (void)out_size; (void)ws_size;

  const float* x[2] = {(const float*)d_in[0], (const float*)d_in[3]};
  const int* ei[2] = {(const int*)d_in[1], (const int*)d_in[4]};
  const float* ea[2] = {(const float*)d_in[2], (const float*)d_in[5]};
  const float* dm = (const float*)d_in[6];
  const float* nv = (const float*)d_in[7];
  const int* od = (const int*)d_in[8];
  const float* Wl[2] = {(const float*)d_in[9], (const float*)d_in[16]};
  const float* bl[2] = {(const float*)d_in[10], (const float*)d_in[17]};
  const float* Wr[2] = {(const float*)d_in[11], (const float*)d_in[18]};
  const float* br[2] = {(const float*)d_in[12], (const float*)d_in[19]};
  const float* We[2] = {(const float*)d_in[13], (const float*)d_in[20]};
  const float* att[2] = {(const float*)d_in[14], (const float*)d_in[21]};
  const float* bia[2] = {(const float*)d_in[15], (const float*)d_in[22]};
  const float* eW1 = (const float*)d_in[23];
  const float* eW2 = (const float*)d_in[24];
  const float* eW3 = (const float*)d_in[25];
  const float* eW4 = (const float*)d_in[26];
  const float* eWo = (const float*)d_in[27];
  const float* fW1 = (const float*)d_in[28];
  const float* fW2 = (const float*)d_in[29];
  const float* fW3 = (const float*)d_in[30];
  const float* fW4 = (const float*)d_in[31];
  const float* fWo = (const float*)d_in[32];
  const float* fg[4] = {(const float*)d_in[33], (const float*)d_in[35], (const float*)d_in[37], (const float*)d_in[39]};
  const float* fb[4] = {(const float*)d_in[34], (const float*)d_in[36], (const float*)d_in[38], (const float*)d_in[40]};

  float* out_inf = (float*)d_out;
  float* out_a1 = out_inf + NB;
  float* out_a2 = out_a1 + (size_t)ET * 4;
  float* out_evo = out_a2 + (size_t)ET * 4;

  // ---- workspace carve ----
  char* base = (char*)d_ws;
  size_t cur = 0;
  auto carve = [&](size_t bytes) -> char* {
    char* p = base + cur;
    cur += (bytes + 255) & ~(size_t)255;
    return p;
  };
  u16* bufA = (u16*)carve((size_t)NB * 256 * 2);
  u16* bufB = (u16*)carve((size_t)NB * 256 * 2);
  u16* bufC = (u16*)carve((size_t)NB * 160 * 2);   // h4act (cols 0-127) + S (128-132) + zeros
  float* n1 = (float*)carve((size_t)NN * 128 * 4);
  float* n2 = (float*)carve((size_t)NN * 128 * 4);
  float* Qo = (float*)carve((size_t)NN * 256 * 4);
  float* Qd = (float*)carve((size_t)NN * 256 * 4);
  float* xl = (float*)carve((size_t)NN * 128 * 4);
  float* xr = (float*)carve((size_t)NN * 128 * 4);
  int* cnt = (int*)carve((size_t)(NN + 1) * 4);
  int* wr = (int*)carve((size_t)NN * 4);
  int* cs = (int*)carve((size_t)(NN + 1) * 4);
  int2* csr = (int2*)carve((size_t)ET * 8);
  float* m_out = (float*)carve((size_t)NN * 4 * 4);
  float* den_out = (float*)carve((size_t)NN * 4 * 4);
  float* asum = (float*)carve((size_t)NN * 8 * 4);
  float* scr = (float*)carve((size_t)ET * 4 * 4);
  float* distb = (float*)carve((size_t)NB * 4);
  float* w512 = (float*)carve(1024);
  float* W1T = (float*)carve(512 * 256 * 4);
  float* stats = (float*)carve(1792 * 4);
  float* st[4] = {stats, stats + 512, stats + 1024, stats + 1536};
  u16* eW2b = (u16*)carve(256 * 256 * 2);
  u16* eW3b = (u16*)carve(256 * 256 * 2);
  u16* eW4b = (u16*)carve(128 * 256 * 2);
  u16* eWob = (u16*)carve(64 * 128 * 2);
  u16* fW2b = (u16*)carve(256 * 256 * 2);
  u16* fW3b = (u16*)carve(256 * 256 * 2);
  u16* fW4b = (u16*)carve(128 * 256 * 2);
  u16* combW = (u16*)carve(256 * 160 * 2);

  // ---- prep (one kernel) ----
  k_prep<<<1825, 256, 0, stream>>>(eW2, eW3, eW4, eWo, fW1, fW2, fW3, fW4, eW1,
                                   eW2b, eW3b, eW4b, eWob, fW2b, fW3b, fW4b,
                                   W1T, w512, combW);
  hipMemsetAsync(stats, 0, 1792 * 4, stream);
  k_sprep<<<NB / 256, 256, 0, stream>>>(od, dm, nv, distb, bufC);

  // ---- GATv2 x2 (CSR-based) ----
  float* nout[2] = {n1, n2};
  float* aout[2] = {out_a1, out_a2};
  const int EB = (ET + 255) / 256;
  const size_t cwSpan = (size_t)((char*)wr - (char*)cnt) + (size_t)NN * 4;
  for (int gi = 0; gi < 2; ++gi) {
    hipMemsetAsync(cnt, 0, cwSpan, stream);
    k_count<<<EB, 256, 0, stream>>>(ei[gi], cnt);
    k_scan<<<1, 1024, 0, stream>>>(cnt, cs);
    k_fill<<<EB, 256, 0, stream>>>(ei[gi], cs, wr, csr);
    k_asum<<<NN / 4, 256, 0, stream>>>(csr, cs, ea[gi], asum);
    k_xlr<<<NN / 2, 256, 0, stream>>>(x[gi], Wl[gi], bl[gi], Wr[gi], br[gi], xl, xr);
    k_scr<<<2048, 256, 0, stream>>>(xl, xr, ei[gi], ea[gi], asum, We[gi], att[gi], scr);
    k_nodered<<<NN / 4, 256, 0, stream>>>(scr, csr, cs, xl, bia[gi], m_out, den_out, nout[gi]);
    k_alpha<<<(ET * 4 + 255) / 256, 256, 0, stream>>>(scr, ei[gi], m_out, den_out, aout[gi]);
  }

  // ---- evo ----
  k_qtab<<<NN / 16, 256, 0, stream>>>(n1, n2, W1T, Qo, Qd);
  k_evo1<<<NB * 64 / 256, 256, 0, stream>>>(Qo, Qd, od, distb, w512, bufA);

  const float invB = 1.0f / (float)NB;
  const int G2 = NB / 128 * 2, G1 = NB / 128;
  gemm_bf16<4, 0, 2><<<G2, 256, 0, stream>>>(bufA, eW2b, 256, 256, 256, bufB, 256, nullptr, nullptr);
  gemm_bf16<4, 0, 2><<<G2, 256, 0, stream>>>(bufB, eW3b, 256, 256, 256, bufA, 256, nullptr, nullptr);
  gemm_bf16<4, 0, 1><<<G1, 256, 0, stream>>>(bufA, eW4b, 256, 256, 128, bufC, 160, nullptr, nullptr);
  gemm_bf16<2, 2, 1><<<G1, 256, 0, stream>>>(bufC, eWob, 128, 160, 64, nullptr, 0, out_evo, nullptr);

  // ---- flow (L1 folded: pre1 = h4 @ combW^T, K=160 includes S columns) ----
  gemm_bf16<4, 1, 2><<<G2, 256, 0, stream>>>(bufC, combW, 160, 160, 256, bufA, 256, nullptr, st[0]);
  k_bnact<<<NB * 256 / 8 / 256, 256, 0, stream>>>(bufA, bufB, st[0], fg[0], fb[0], 256, invB);
  gemm_bf16<4, 1, 2><<<G2, 256, 0, stream>>>(bufB, fW2b, 256, 256, 256, bufA, 256, nullptr, st[1]);
  k_bnact<<<NB * 256 / 8 / 256, 256, 0, stream>>>(bufA, bufB, st[1], fg[1], fb[1], 256, invB);
  gemm_bf16<4, 1, 2><<<G2, 256, 0, stream>>>(bufB, fW3b, 256, 256, 256, bufA, 256, nullptr, st[2]);
  k_bnact<<<NB * 256 / 8 / 256, 256, 0, stream>>>(bufA, bufB, st[2], fg[2], fb[2], 256, invB);
  gemm_bf16<4, 1, 1><<<G1, 256, 0, stream>>>(bufB, fW4b, 256, 256, 128, bufA, 128, nullptr, st[3]);
  k_fout4<<<NB / 256, 256, 0, stream>>>(bufA, st[3], fg[3], fb[3], fWo, out_inf, invB);
}

// Round 5
// 1388.845 us; speedup vs baseline: 2.0404x; 1.1645x over previous
//
#include <hip/hip_runtime.h>

typedef unsigned short u16;
typedef unsigned int u32;

#define NN 10000      // nodes
#define NE 320000     // edges
#define ET 330000     // edges + self loops
#define NB 262144     // batch

typedef __attribute__((ext_vector_type(8))) short bf16x8;
typedef __attribute__((ext_vector_type(4))) float f32x4;

__device__ __forceinline__ u16 f2b(float f) {
  u32 u = __float_as_uint(f);
  u += 0x7fffu + ((u >> 16) & 1u);
  return (u16)(u >> 16);
}
__device__ __forceinline__ float b2f(u16 h) {
  return __uint_as_float(((u32)h) << 16);
}
__device__ __forceinline__ float lrelu(float v, float s) { return v > 0.f ? v : v * s; }

__device__ __forceinline__ void g2lds16(const void* g, void* l) {
  __builtin_amdgcn_global_load_lds((const __attribute__((address_space(1))) void*)g,
                                   (__attribute__((address_space(3))) void*)l, 16, 0, 0);
}

// ---------------- merged prep ----------------
// blocks: [0,256) eW2b | [256,512) eW3b | [512,640) eW4b | [640,672) eWob
//         [672,928) fW2b | [928,1184) fW3b | [1184,1312) fW4b
//         [1312,1568) W1T | 1568 w512 | [1569,1825) combW
__global__ __launch_bounds__(256) void k_prep(const float* __restrict__ eW2, const float* __restrict__ eW3,
                                              const float* __restrict__ eW4, const float* __restrict__ eWo,
                                              const float* __restrict__ fW1, const float* __restrict__ fW2,
                                              const float* __restrict__ fW3, const float* __restrict__ fW4,
                                              const float* __restrict__ eW1,
                                              u16* eW2b, u16* eW3b, u16* eW4b, u16* eWob,
                                              u16* fW2b, u16* fW3b, u16* fW4b,
                                              float* W1T, float* w512, u16* combW) {
  const int blk = blockIdx.x, tid = threadIdx.x;
  if (blk < 256) {
    int t = blk * 256 + tid; eW2b[t] = f2b(eW2[t]);
  } else if (blk < 512) {
    int t = (blk - 256) * 256 + tid; eW3b[t] = f2b(eW3[t]);
  } else if (blk < 640) {
    int t = (blk - 512) * 256 + tid; eW4b[t] = f2b(eW4[t]);
  } else if (blk < 672) {
    int t = (blk - 640) * 256 + tid; eWob[t] = f2b(eWo[t]);
  } else if (blk < 928) {
    int t = (blk - 672) * 256 + tid; fW2b[t] = f2b(fW2[t]);
  } else if (blk < 1184) {
    int t = (blk - 928) * 256 + tid; fW3b[t] = f2b(fW3[t]);
  } else if (blk < 1312) {
    int t = (blk - 1184) * 256 + tid; fW4b[t] = f2b(fW4[t]);
  } else if (blk < 1568) {
    int m = blk - 1312;
    for (int k = tid; k < 512; k += 256) W1T[(size_t)k * 256 + m] = eW1[(size_t)m * 513 + k];
  } else if (blk == 1568) {
    w512[tid] = eW1[(size_t)tid * 513 + 512];
  } else {
    int m = blk - 1569;
    int k = tid;
    if (k < 160) {
      float v = 0.f;
      if (k < 128) {
        const float* fr = fW1 + (size_t)m * 69;
        for (int j = 0; j < 64; ++j) v += fr[j] * eWo[(size_t)j * 128 + k];
      } else if (k < 133) {
        v = fW1[(size_t)m * 69 + 64 + (k - 128)];
      }
      combW[(size_t)m * 160 + k] = f2b(v);
    }
  }
}

// distb + S columns (128..159) of bufC
__global__ __launch_bounds__(256) void k_sprep(const int* __restrict__ od, const float* __restrict__ dm,
                                               const float* __restrict__ nv,
                                               float* __restrict__ distb, u16* __restrict__ bufC) {
  int b = blockIdx.x * 256 + threadIdx.x;
  int o = od[b * 2], d = od[b * 2 + 1];
  float dist = dm[(size_t)o * NN + d];
  distb[b] = dist;
  u16 tmp[32];
  tmp[0] = f2b(nv[o * 2]);
  tmp[1] = f2b(nv[d * 2]);
  tmp[2] = f2b(nv[o * 2 + 1]);
  tmp[3] = f2b(nv[d * 2 + 1]);
  tmp[4] = f2b(dist);
#pragma unroll
  for (int k = 5; k < 32; ++k) tmp[k] = 0;
  u16* p = bufC + (size_t)b * 160 + 128;
#pragma unroll
  for (int k = 0; k < 4; ++k) *(bf16x8*)(p + k * 8) = *(bf16x8*)(tmp + k * 8);
}

// ---------------- CSR build ----------------
__global__ __launch_bounds__(256) void k_count(const int* __restrict__ ei, int* __restrict__ cnt) {
  int t = blockIdx.x * 256 + threadIdx.x;
  if (t >= ET) return;
  int d = (t < NE) ? ei[NE + t] : (t - NE);
  atomicAdd(&cnt[d], 1);
}

__global__ __launch_bounds__(1024) void k_scan(const int* __restrict__ cnt, int* __restrict__ cs) {
  __shared__ int part[1024];
  int tid = threadIdx.x;
  int base = tid * 10;
  int local[10];
  int s = 0;
#pragma unroll
  for (int i = 0; i < 10; ++i) {
    int idx = base + i;
    int v = (idx < NN) ? cnt[idx] : 0;
    local[i] = s; s += v;
  }
  part[tid] = s;
  __syncthreads();
  for (int off = 1; off < 1024; off <<= 1) {
    int v = (tid >= off) ? part[tid - off] : 0;
    __syncthreads();
    part[tid] += v;
    __syncthreads();
  }
  int pre = (tid > 0) ? part[tid - 1] : 0;
#pragma unroll
  for (int i = 0; i < 10; ++i) {
    int idx = base + i;
    if (idx < NN) cs[idx] = pre + local[i];
  }
  if (tid == 1023) cs[NN] = part[1023];
}

__global__ __launch_bounds__(256) void k_fill(const int* __restrict__ ei, const int* __restrict__ cs,
                                              int* __restrict__ wr, int2* __restrict__ csr) {
  int t = blockIdx.x * 256 + threadIdx.x;
  if (t >= ET) return;
  int s, d;
  if (t < NE) { s = ei[t]; d = ei[NE + t]; } else { s = t - NE; d = s; }
  int pos = atomicAdd(&wr[d], 1);
  csr[cs[d] + pos] = make_int2(t, s);
}

__global__ __launch_bounds__(256) void k_asum(const int2* __restrict__ csr, const int* __restrict__ cs,
                                              const float* __restrict__ ea, float* __restrict__ asum) {
  int wid = (blockIdx.x * 256 + threadIdx.x) >> 6;
  int lane = threadIdx.x & 63;
  int beg = cs[wid], end = cs[wid + 1];
  int j = lane & 7, slot = lane >> 3;
  float acc = 0.f;
  for (int i = beg + slot; i < end; i += 8) {
    int e = csr[i].x;
    if (e < NE) acc += ea[(size_t)e * 8 + j];
  }
  acc += __shfl_xor(acc, 8);
  acc += __shfl_xor(acc, 16);
  acc += __shfl_xor(acc, 32);
  if (lane < 8) {
    float dr = (float)(end - beg - 1);
    asum[(size_t)wid * 8 + lane] = acc / fmaxf(dr, 1.f);
  }
}

// ---------------- GAT ----------------
__global__ __launch_bounds__(256) void k_xlr(const float* __restrict__ x,
                                             const float* __restrict__ Wl, const float* __restrict__ bl,
                                             const float* __restrict__ Wr, const float* __restrict__ br,
                                             float* __restrict__ xl, float* __restrict__ xr) {
  __shared__ float sx[128];
  int nb = blockIdx.x * 2;
  for (int i = threadIdx.x; i < 128; i += 256) sx[i] = x[(size_t)nb * 64 + i];
  __syncthreads();
  int half = threadIdx.x >> 7;
  int node = nb + half;
  int m = threadIdx.x & 127;
  const float* xv = sx + (half << 6);
  float al = bl[m], ar = br[m];
  const float* wl = Wl + (size_t)m * 64;
  const float* wr = Wr + (size_t)m * 64;
#pragma unroll 8
  for (int k = 0; k < 64; ++k) { float xk = xv[k]; al += xk * wl[k]; ar += xk * wr[k]; }
  xl[(size_t)node * 128 + m] = al;
  xr[(size_t)node * 128 + m] = ar;
}

__global__ __launch_bounds__(256) void k_scr(const float* __restrict__ xl, const float* __restrict__ xr,
                                             const int* __restrict__ ei, const float* __restrict__ ea,
                                             const float* __restrict__ mattr,
                                             const float* __restrict__ We, const float* __restrict__ att,
                                             float* __restrict__ scr) {
  const int lane = threadIdx.x & 63;
  const int sub = lane & 31;
  const int half = lane >> 5;
  float4 w0[4], w1[4];
#pragma unroll
  for (int c = 0; c < 4; ++c) {
    const float* wp = We + (size_t)(sub * 4 + c) * 8;
    w0[c] = *(const float4*)wp;
    w1[c] = *(const float4*)(wp + 4);
  }
  const float4 attv = *(const float4*)(att + sub * 4);
  const int gw = (blockIdx.x * 256 + threadIdx.x) >> 6;
  const int nw = gridDim.x * 4;
  for (int p = gw; p < ET / 2; p += nw) {
    int e = p * 2 + half;
    int s, d; const float* ap;
    if (e < NE) { s = ei[e]; d = ei[NE + e]; ap = ea + (size_t)e * 8; }
    else { s = e - NE; d = s; ap = mattr + (size_t)(e - NE) * 8; }
    float4 a0 = *(const float4*)ap;
    float4 a1 = *(const float4*)(ap + 4);
    float4 xlv = *(const float4*)(xl + (size_t)s * 128 + sub * 4);
    float4 xrv = *(const float4*)(xr + (size_t)d * 128 + sub * 4);
    const float* xle = (const float*)&xlv;
    const float* xre = (const float*)&xrv;
    const float* ate = (const float*)&attv;
    float psum = 0.f;
#pragma unroll
    for (int c = 0; c < 4; ++c) {
      float em = a0.x * w0[c].x + a0.y * w0[c].y + a0.z * w0[c].z + a0.w * w0[c].w
               + a1.x * w1[c].x + a1.y * w1[c].y + a1.z * w1[c].z + a1.w * w1[c].w;
      float v = xle[c] + xre[c] + em;
      v = v > 0.f ? v : 0.2f * v;
      psum += v * ate[c];
    }
    psum += __shfl_xor(psum, 1);
    psum += __shfl_xor(psum, 2);
    psum += __shfl_xor(psum, 4);
    if ((sub & 7) == 0) scr[(size_t)e * 4 + (sub >> 3)] = psum;
  }
}

__global__ __launch_bounds__(256) void k_nodered(const float* __restrict__ scr, const int2* __restrict__ csr,
                                                 const int* __restrict__ cs, const float* __restrict__ xl,
                                                 const float* __restrict__ bias,
                                                 float* __restrict__ m_out, float* __restrict__ den_out,
                                                 float* __restrict__ nout) {
  int d = (blockIdx.x * 256 + threadIdx.x) >> 6;
  int lane = threadIdx.x & 63;
  int h0 = lane >> 5;
  int beg = cs[d], end = cs[d + 1];
  float mx0 = -3.4e38f, mx1 = -3.4e38f;
  for (int i = beg; i < end; ++i) {
    int e = csr[i].x;
    mx0 = fmaxf(mx0, scr[(size_t)e * 4 + h0]);
    mx1 = fmaxf(mx1, scr[(size_t)e * 4 + h0 + 2]);
  }
  float acc0 = 0.f, acc1 = 0.f, dn0 = 0.f, dn1 = 0.f;
  for (int i = beg; i < end; ++i) {
    int2 es = csr[i];
    float ex0 = __expf(scr[(size_t)es.x * 4 + h0] - mx0);
    float ex1 = __expf(scr[(size_t)es.x * 4 + h0 + 2] - mx1);
    dn0 += ex0; dn1 += ex1;
    const float* xp = xl + (size_t)es.y * 128;
    acc0 += ex0 * xp[lane];
    acc1 += ex1 * xp[64 + lane];
  }
  if (lane == 0 || lane == 32) {
    m_out[d * 4 + h0] = mx0;     m_out[d * 4 + h0 + 2] = mx1;
    den_out[d * 4 + h0] = dn0;   den_out[d * 4 + h0 + 2] = dn1;
  }
  nout[(size_t)d * 128 + lane] = fmaxf(acc0 / dn0 + bias[lane], 0.f);
  nout[(size_t)d * 128 + 64 + lane] = fmaxf(acc1 / dn1 + bias[64 + lane], 0.f);
}

__global__ __launch_bounds__(256) void k_alpha(const float* __restrict__ scr, const int* __restrict__ ei,
                                               const float* __restrict__ m, const float* __restrict__ den,
                                               float* __restrict__ aout) {
  int t = blockIdx.x * 256 + threadIdx.x;
  if (t >= ET * 4) return;
  int e = t >> 2, h = t & 3;
  int d = (e < NE) ? ei[NE + e] : (e - NE);
  aout[t] = __expf(scr[t] - m[d * 4 + h]) / den[d * 4 + h];
}

// ---------------- evo L1 factorization (bf16 tables) ----------------
__global__ __launch_bounds__(256) void k_qtab(const float* __restrict__ n1, const float* __restrict__ n2,
                                              const float* __restrict__ W1T,
                                              u16* __restrict__ Qo, u16* __restrict__ Qd) {
  __shared__ float s1[2048], s2[2048];
  int nb = blockIdx.x * 16;
  for (int i = threadIdx.x; i < 2048; i += 256) {
    s1[i] = n1[(size_t)nb * 128 + i];
    s2[i] = n2[(size_t)nb * 128 + i];
  }
  __syncthreads();
  int m = threadIdx.x;
  float qo[16], qd[16];
#pragma unroll
  for (int i = 0; i < 16; ++i) { qo[i] = 0.f; qd[i] = 0.f; }
#pragma unroll 2
  for (int k = 0; k < 128; ++k) {
    float w0 = W1T[(size_t)k * 256 + m];
    float w1 = W1T[(size_t)(128 + k) * 256 + m];
    float w2 = W1T[(size_t)(256 + k) * 256 + m];
    float w3 = W1T[(size_t)(384 + k) * 256 + m];
#pragma unroll
    for (int i = 0; i < 16; ++i) {
      float a = s1[i * 128 + k], b = s2[i * 128 + k];
      qo[i] += a * w0 + b * w2;
      qd[i] += a * w1 + b * w3;
    }
  }
#pragma unroll
  for (int i = 0; i < 16; ++i) {
    Qo[(size_t)(nb + i) * 256 + m] = f2b(qo[i]);
    Qd[(size_t)(nb + i) * 256 + m] = f2b(qd[i]);
  }
}

__global__ __launch_bounds__(256) void k_evo1(const u16* __restrict__ Qo, const u16* __restrict__ Qd,
                                              const int* __restrict__ od, const float* __restrict__ distb,
                                              const float* __restrict__ w512, u16* __restrict__ h1) {
  __shared__ float sw[256];
  sw[threadIdx.x] = w512[threadIdx.x];
  __syncthreads();
  int t = blockIdx.x * 256 + threadIdx.x;
  int b = t >> 5, mq = (t & 31) << 3;
  int o = od[b * 2], d = od[b * 2 + 1];
  float dist = distb[b];
  bf16x8 qa = *(const bf16x8*)(Qo + (size_t)o * 256 + mq);
  bf16x8 qc = *(const bf16x8*)(Qd + (size_t)d * 256 + mq);
  bf16x8 r;
#pragma unroll
  for (int j = 0; j < 8; ++j) {
    float v = b2f((u16)qa[j]) + b2f((u16)qc[j]) + dist * sw[mq + j];
    r[j] = (short)f2b(lrelu(v, 0.01f));
  }
  *(bf16x8*)(h1 + (size_t)b * 256 + mq) = r;
}

// ---------------- 256-row MFMA GEMM, 512 threads / 8 waves (2x4) ----------------
// C(B x M) = act(A(B x K, stride lda)) @ W(M x K)^T ;  M = NF*64
// BNA: apply per-column BN(scale,shift)+leaky to A fragments (stats from stin,g,b)
// EPI: 0 = leaky(0.01)->bf16 | 1 = raw bf16 + column stats (sum,sumsq)
template <int NF, int EPI, int BNA>
__global__ __launch_bounds__(512) void gemm256(const u16* __restrict__ A, const u16* __restrict__ W,
                                               int K, size_t lda,
                                               u16* __restrict__ obf, int ld_bf,
                                               float* __restrict__ stats,
                                               const float* __restrict__ stin, const float* __restrict__ gg,
                                               const float* __restrict__ bb, float invB) {
  constexpr int M = NF * 64;
  constexpr int CPW = 2 + NF / 2;           // stage chunks per wave
  __shared__ alignas(16) u16 Alds[2][256 * 32];
  __shared__ alignas(16) u16 Blds[2][M * 32];
  __shared__ float sS[256], sT[256];
  const int tid = threadIdx.x;
  const int lane = tid & 63;
  const int w = tid >> 6;
  const int wr = w >> 2, wc = w & 3;
  const size_t rowBase = (size_t)blockIdx.x * 256;

  if (BNA) {
    for (int c = tid; c < K; c += 512) {
      float mu = stin[c] * invB;
      float var = stin[K + c] * invB - mu * mu;
      float sc = rsqrtf(var + 1e-5f) * gg[c];
      sS[c] = sc;
      sT[c] = bb[c] - mu * sc;
    }
    __syncthreads();  // before any staging: full drain is free here
  }

  f32x4 acc[8][NF];
  const f32x4 z4 = {0.f, 0.f, 0.f, 0.f};
#pragma unroll
  for (int m = 0; m < 8; ++m)
#pragma unroll
    for (int n = 0; n < NF; ++n) acc[m][n] = z4;

  const int crow = lane >> 2;
  const int ccol = (lane & 3) << 3;
  const int KT = K >> 5;

  auto stage = [&](int buf, int kb) {
#pragma unroll
    for (int i = 0; i < CPW; ++i) {
      const int c = w * CPW + i;
      if (c < 16) {
        const u16* src = A + (rowBase + (c << 4) + crow) * lda + kb + ccol;
        g2lds16(src, &Alds[buf][(c << 4) << 5]);
      } else {
        const u16* src = W + (size_t)(((c - 16) << 4) + crow) * K + kb + ccol;
        g2lds16(src, &Blds[buf][((c - 16) << 4) << 5]);
      }
    }
  };

  stage(0, 0);
  int cur = 0;
  const int lr = lane & 15, lk = (lane >> 4) << 3;
  for (int kt = 0; kt < KT; ++kt) {
    const int kb = kt << 5;
    if (kt + 1 < KT) {
      stage(cur ^ 1, kb + 32);
      if constexpr (NF == 4)
        asm volatile("s_waitcnt vmcnt(4)" ::: "memory");
      else
        asm volatile("s_waitcnt vmcnt(3)" ::: "memory");
    } else {
      asm volatile("s_waitcnt vmcnt(0)" ::: "memory");
    }
    __builtin_amdgcn_s_barrier();

    float sv[8], tv[8];
    if (BNA) {
      float4 s0 = *(const float4*)&sS[kb + lk];
      float4 s1 = *(const float4*)&sS[kb + lk + 4];
      float4 t0 = *(const float4*)&sT[kb + lk];
      float4 t1 = *(const float4*)&sT[kb + lk + 4];
      sv[0] = s0.x; sv[1] = s0.y; sv[2] = s0.z; sv[3] = s0.w;
      sv[4] = s1.x; sv[5] = s1.y; sv[6] = s1.z; sv[7] = s1.w;
      tv[0] = t0.x; tv[1] = t0.y; tv[2] = t0.z; tv[3] = t0.w;
      tv[4] = t1.x; tv[5] = t1.y; tv[6] = t1.z; tv[7] = t1.w;
    }
    bf16x8 bfr[NF];
#pragma unroll
    for (int n = 0; n < NF; ++n)
      bfr[n] = *(const bf16x8*)&Blds[cur][((((wc * NF + n) << 4) + lr) << 5) + lk];
#pragma unroll
    for (int m = 0; m < 8; ++m) {
      bf16x8 af = *(const bf16x8*)&Alds[cur][(((wr << 7) + (m << 4) + lr) << 5) + lk];
      if (BNA) {
        bf16x8 o;
#pragma unroll
        for (int j = 0; j < 8; ++j) {
          float v = fmaf(b2f((u16)af[j]), sv[j], tv[j]);
          v = v > 0.f ? v : v * 0.01f;
          o[j] = (short)f2b(v);
        }
        af = o;
      }
#pragma unroll
      for (int n = 0; n < NF; ++n)
        acc[m][n] = __builtin_amdgcn_mfma_f32_16x16x32_bf16(af, bfr[n], acc[m][n], 0, 0, 0);
    }
    __builtin_amdgcn_s_barrier();
    cur ^= 1;
  }

  const int lg = lane >> 4;
  float csm[NF], cq[NF];
#pragma unroll
  for (int n = 0; n < NF; ++n) { csm[n] = 0.f; cq[n] = 0.f; }
#pragma unroll
  for (int m = 0; m < 8; ++m) {
#pragma unroll
    for (int n = 0; n < NF; ++n) {
      const int col = wc * (NF * 16) + (n << 4) + lr;
#pragma unroll
      for (int j = 0; j < 4; ++j) {
        const size_t row = rowBase + (wr << 7) + (m << 4) + (lg << 2) + j;
        float v = acc[m][n][j];
        if (EPI == 0) {
          v = v > 0.f ? v : v * 0.01f;
          obf[row * ld_bf + col] = f2b(v);
        } else {
          obf[row * ld_bf + col] = f2b(v);
          csm[n] += v; cq[n] += v * v;
        }
      }
    }
  }
  if (EPI == 1) {
#pragma unroll
    for (int n = 0; n < NF; ++n) {
      float s = csm[n], q = cq[n];
      s += __shfl_xor(s, 16); s += __shfl_xor(s, 32);
      q += __shfl_xor(q, 16); q += __shfl_xor(q, 32);
      if (lane < 16) {
        const int col = wc * (NF * 16) + (n << 4) + lane;
        atomicAdd(&stats[col], s);
        atomicAdd(&stats[M + col], q);
      }
    }
  }
}

// ---------------- legacy 128-tile GEMM (only for eWo: M=64, f32 out) ----------------
template <int NF>
__global__ __launch_bounds__(256) void gemm_f32out(const u16* __restrict__ A, const u16* __restrict__ W,
                                                   int K, size_t lda, int M, float* __restrict__ of32) {
  constexpr int CW = NF * 16;
  __shared__ alignas(16) u16 Alds[2][128 * 32];
  __shared__ alignas(16) u16 Blds[2][CW * 2 * 32];
  const int lane = threadIdx.x & 63;
  const int w = threadIdx.x >> 6;
  const int wr = w >> 1, wc = w & 1;
  const size_t rowBase = (size_t)blockIdx.x * 128;

  f32x4 acc[4][NF];
  const f32x4 z4 = {0.f, 0.f, 0.f, 0.f};
#pragma unroll
  for (int m = 0; m < 4; ++m)
#pragma unroll
    for (int n = 0; n < NF; ++n) acc[m][n] = z4;

  const int sr = (w << 4) + (lane >> 2);
  const int sc = (lane & 3) << 3;
  const int KT = K >> 5;

  auto stage = [&](int buf, int kb) {
#pragma unroll
    for (int i = 0; i < 2; ++i) {
      const u16* src = A + (rowBase + (i << 6) + sr) * lda + kb + sc;
      g2lds16(src, &Alds[buf][((i << 6) + (w << 4)) << 5]);
    }
#pragma unroll
    for (int i = 0; i < NF / 2; ++i) {
      const u16* src = W + (size_t)((i << 6) + sr) * K + kb + sc;
      g2lds16(src, &Blds[buf][((i << 6) + (w << 4)) << 5]);
    }
  };

  stage(0, 0);
  int cur = 0;
  for (int kt = 0; kt < KT; ++kt) {
    if (kt + 1 < KT) {
      stage(cur ^ 1, (kt + 1) << 5);
      asm volatile("s_waitcnt vmcnt(3)" ::: "memory");
    } else {
      asm volatile("s_waitcnt vmcnt(0)" ::: "memory");
    }
    __builtin_amdgcn_s_barrier();
    const int lr = lane & 15, lk = (lane >> 4) << 3;
    bf16x8 af[4], bfr[NF];
#pragma unroll
    for (int m = 0; m < 4; ++m)
      af[m] = *(const bf16x8*)&Alds[cur][(((wr << 6) + (m << 4) + lr) << 5) + lk];
#pragma unroll
    for (int n = 0; n < NF; ++n)
      bfr[n] = *(const bf16x8*)&Blds[cur][((wc * CW + (n << 4) + lr) << 5) + lk];
#pragma unroll
    for (int m = 0; m < 4; ++m)
#pragma unroll
      for (int n = 0; n < NF; ++n)
        acc[m][n] = __builtin_amdgcn_mfma_f32_16x16x32_bf16(af[m], bfr[n], acc[m][n], 0, 0, 0);
    __builtin_amdgcn_s_barrier();
    cur ^= 1;
  }

  const int lr = lane & 15, lg = lane >> 4;
#pragma unroll
  for (int m = 0; m < 4; ++m) {
#pragma unroll
    for (int n = 0; n < NF; ++n) {
      const int col = wc * CW + (n << 4) + lr;
      if (col >= M) continue;
#pragma unroll
      for (int j = 0; j < 4; ++j) {
        const size_t row = rowBase + (wr << 6) + (m << 4) + (lg << 2) + j;
        of32[row * M + col] = acc[m][n][j];
      }
    }
  }
}

// ---------------- fused BN4 + final dot ----------------
__global__ __launch_bounds__(256) void k_fout4(const u16* __restrict__ pre, const float* __restrict__ st,
                                               const float* __restrict__ g, const float* __restrict__ b,
                                               const float* __restrict__ W, float* __restrict__ out,
                                               float invB) {
  __shared__ float smu[128], srs[128], sg[128], sb[128], sw[128];
  if (threadIdx.x < 128) {
    int c = threadIdx.x;
    float mu = st[c] * invB;
    float var = st[128 + c] * invB - mu * mu;
    smu[c] = mu;
    srs[c] = rsqrtf(var + 1e-5f);
    sg[c] = g[c];
    sb[c] = b[c];
    sw[c] = W[c];
  }
  __syncthreads();
  int bi = blockIdx.x * 256 + threadIdx.x;
  const u16* hp = pre + (size_t)bi * 128;
  float acc = 0.f;
#pragma unroll
  for (int k = 0; k < 128; k += 8) {
    bf16x8 u = *(const bf16x8*)(hp + k);
#pragma unroll
    for (int j = 0; j < 8; ++j) {
      int c = k + j;
      float v = (b2f((u16)u[j]) - smu[c]) * srs[c] * sg[c] + sb[c];
      v = b2f(f2b(lrelu(v, 0.01f)));
      acc += v * sw[c];
    }
  }
  out[bi] = acc;
}

// ---------------- launch ----------------
extern "C" void kernel_launch(void* const* d_in, const int* in_sizes, int n_in,
                              void* d_out, int out_size, void* d_ws, size_t ws_size,
                              hipStream_t stream) {
  (void)in_sizes; (void)n_in; (void)out_size; (void)ws_size;

  const float* x[2] = {(const float*)d_in[0], (const float*)d_in[3]};
  const int* ei[2] = {(const int*)d_in[1], (const int*)d_in[4]};
  const float* ea[2] = {(const float*)d_in[2], (const float*)d_in[5]};
  const float* dm = (const float*)d_in[6];
  const float* nv = (const float*)d_in[7];
  const int* od = (const int*)d_in[8];
  const float* Wl[2] = {(const float*)d_in[9], (const float*)d_in[16]};
  const float* bl[2] = {(const float*)d_in[10], (const float*)d_in[17]};
  const float* Wr[2] = {(const float*)d_in[11], (const float*)d_in[18]};
  const float* br[2] = {(const float*)d_in[12], (const float*)d_in[19]};
  const float* We[2] = {(const float*)d_in[13], (const float*)d_in[20]};
  const float* att[2] = {(const float*)d_in[14], (const float*)d_in[21]};
  const float* bia[2] = {(const float*)d_in[15], (const float*)d_in[22]};
  const float* eW1 = (const float*)d_in[23];
  const float* eW2 = (const float*)d_in[24];
  const float* eW3 = (const float*)d_in[25];
  const float* eW4 = (const float*)d_in[26];
  const float* eWo = (const float*)d_in[27];
  const float* fW1 = (const float*)d_in[28];
  const float* fW2 = (const float*)d_in[29];
  const float* fW3 = (const float*)d_in[30];
  const float* fW4 = (const float*)d_in[31];
  const float* fWo = (const float*)d_in[32];
  const float* fg[4] = {(const float*)d_in[33], (const float*)d_in[35], (const float*)d_in[37], (const float*)d_in[39]};
  const float* fb[4] = {(const float*)d_in[34], (const float*)d_in[36], (const float*)d_in[38], (const float*)d_in[40]};

  float* out_inf = (float*)d_out;
  float* out_a1 = out_inf + NB;
  float* out_a2 = out_a1 + (size_t)ET * 4;
  float* out_evo = out_a2 + (size_t)ET * 4;

  // ---- workspace carve ----
  char* base = (char*)d_ws;
  size_t cur = 0;
  auto carve = [&](size_t bytes) -> char* {
    char* p = base + cur;
    cur += (bytes + 255) & ~(size_t)255;
    return p;
  };
  u16* bufA = (u16*)carve((size_t)NB * 256 * 2);
  u16* bufB = (u16*)carve((size_t)NB * 256 * 2);
  u16* bufC = (u16*)carve((size_t)NB * 160 * 2);   // h4 (cols 0-127) + S (128-132) + zeros
  float* n1 = (float*)carve((size_t)NN * 128 * 4);
  float* n2 = (float*)carve((size_t)NN * 128 * 4);
  u16* Qob = (u16*)carve((size_t)NN * 256 * 2);
  u16* Qdb = (u16*)carve((size_t)NN * 256 * 2);
  float* xl = (float*)carve((size_t)NN * 128 * 4);
  float* xr = (float*)carve((size_t)NN * 128 * 4);
  int* cnt = (int*)carve((size_t)(NN + 1) * 4);
  int* wr = (int*)carve((size_t)NN * 4);
  int* cs = (int*)carve((size_t)(NN + 1) * 4);
  int2* csr = (int2*)carve((size_t)ET * 8);
  float* m_out = (float*)carve((size_t)NN * 4 * 4);
  float* den_out = (float*)carve((size_t)NN * 4 * 4);
  float* asum = (float*)carve((size_t)NN * 8 * 4);
  float* scr = (float*)carve((size_t)ET * 4 * 4);
  float* distb = (float*)carve((size_t)NB * 4);
  float* w512 = (float*)carve(1024);
  float* W1T = (float*)carve(512 * 256 * 4);
  float* stats = (float*)carve(1792 * 4);
  float* st[4] = {stats, stats + 512, stats + 1024, stats + 1536};
  u16* eW2b = (u16*)carve(256 * 256 * 2);
  u16* eW3b = (u16*)carve(256 * 256 * 2);
  u16* eW4b = (u16*)carve(128 * 256 * 2);
  u16* eWob = (u16*)carve(64 * 128 * 2);
  u16* fW2b = (u16*)carve(256 * 256 * 2);
  u16* fW3b = (u16*)carve(256 * 256 * 2);
  u16* fW4b = (u16*)carve(128 * 256 * 2);
  u16* combW = (u16*)carve(256 * 160 * 2);

  // ---- prep ----
  k_prep<<<1825, 256, 0, stream>>>(eW2, eW3, eW4, eWo, fW1, fW2, fW3, fW4, eW1,
                                   eW2b, eW3b, eW4b, eWob, fW2b, fW3b, fW4b,
                                   W1T, w512, combW);
  hipMemsetAsync(stats, 0, 1792 * 4, stream);
  k_sprep<<<NB / 256, 256, 0, stream>>>(od, dm, nv, distb, bufC);

  // ---- GATv2 x2 (CSR-based) ----
  float* nout[2] = {n1, n2};
  float* aout[2] = {out_a1, out_a2};
  const int EB = (ET + 255) / 256;
  const size_t cwSpan = (size_t)((char*)wr - (char*)cnt) + (size_t)NN * 4;
  for (int gi = 0; gi < 2; ++gi) {
    hipMemsetAsync(cnt, 0, cwSpan, stream);
    k_count<<<EB, 256, 0, stream>>>(ei[gi], cnt);
    k_scan<<<1, 1024, 0, stream>>>(cnt, cs);
    k_fill<<<EB, 256, 0, stream>>>(ei[gi], cs, wr, csr);
    k_asum<<<NN / 4, 256, 0, stream>>>(csr, cs, ea[gi], asum);
    k_xlr<<<NN / 2, 256, 0, stream>>>(x[gi], Wl[gi], bl[gi], Wr[gi], br[gi], xl, xr);
    k_scr<<<2048, 256, 0, stream>>>(xl, xr, ei[gi], ea[gi], asum, We[gi], att[gi], scr);
    k_nodered<<<NN / 4, 256, 0, stream>>>(scr, csr, cs, xl, bia[gi], m_out, den_out, nout[gi]);
    k_alpha<<<(ET * 4 + 255) / 256, 256, 0, stream>>>(scr, ei[gi], m_out, den_out, aout[gi]);
  }

  // ---- evo ----
  k_qtab<<<NN / 16, 256, 0, stream>>>(n1, n2, W1T, Qob, Qdb);
  k_evo1<<<NB * 32 / 256, 256, 0, stream>>>(Qob, Qdb, od, distb, w512, bufA);

  const float invB = 1.0f / (float)NB;
  const int GB = NB / 256;
  gemm256<4, 0, 0><<<GB, 512, 0, stream>>>(bufA, eW2b, 256, 256, bufB, 256, nullptr, nullptr, nullptr, nullptr, 0.f);
  gemm256<4, 0, 0><<<GB, 512, 0, stream>>>(bufB, eW3b, 256, 256, bufA, 256, nullptr, nullptr, nullptr, nullptr, 0.f);
  gemm256<2, 0, 0><<<GB, 512, 0, stream>>>(bufA, eW4b, 256, 256, bufC, 160, nullptr, nullptr, nullptr, nullptr, 0.f);
  gemm_f32out<2><<<NB / 128, 256, 0, stream>>>(bufC, eWob, 128, 160, 64, out_evo);

  // ---- flow (L1 folded through eWo; BN fused into consumer GEMMs) ----
  gemm256<4, 1, 0><<<GB, 512, 0, stream>>>(bufC, combW, 160, 160, bufA, 256, st[0], nullptr, nullptr, nullptr, 0.f);
  gemm256<4, 1, 1><<<GB, 512, 0, stream>>>(bufA, fW2b, 256, 256, bufB, 256, st[1], st[0], fg[0], fb[0], invB);
  gemm256<4, 1, 1><<<GB, 512, 0, stream>>>(bufB, fW3b, 256, 256, bufA, 256, st[2], st[1], fg[1], fb[1], invB);
  gemm256<2, 1, 1><<<GB, 512, 0, stream>>>(bufA, fW4b, 256, 256, bufB, 128, st[3], st[2], fg[2], fb[2], invB);
  k_fout4<<<NB / 256, 256, 0, stream>>>(bufB, st[3], fg[3], fb[3], fWo, out_inf, invB);
}